// Round 3
// baseline (310.477 us; speedup 1.0000x reference)
//
#include <hip/hip_runtime.h>
#include <hip/hip_bf16.h>
#include <cstdint>

// ---------------- static problem config ----------------
#define D_MODEL   256
#define N_HEADS   8
#define N_LEVELS  4
#define N_POINTS  4
#define D_FFN     1024
#define D_HEAD    32
#define LEN_IN    13294          // 100*100 + 50*50 + 25*25 + 13*13
#define NBATCH    2
#define M_TOK     (NBATCH * LEN_IN)   // 26588
#define M_PAD     26624               // 208*128 = 416*64 = 832*32

__constant__ int c_lvl_h[4] = {100, 50, 25, 13};
__constant__ int c_lvl_w[4] = {100, 50, 25, 13};
__constant__ int c_lvl_s[4] = {0, 10000, 12500, 13125};

typedef __attribute__((ext_vector_type(8))) __bf16 bf16x8;
typedef __attribute__((ext_vector_type(4))) __bf16 bf16x4;
typedef __attribute__((ext_vector_type(4))) float  f32x4;
typedef __attribute__((ext_vector_type(4))) uint32_t u32x4;

__device__ __forceinline__ float bflo(uint32_t w) { return __uint_as_float(w << 16); }
__device__ __forceinline__ float bfhi(uint32_t w) { return __uint_as_float(w & 0xffff0000u); }

// async global->LDS, 16B per lane; lds base wave-uniform (lane i lands at base + i*16)
__device__ __forceinline__ void lds_direct16(const void* g, void* l) {
    __builtin_amdgcn_global_load_lds(
        (const __attribute__((address_space(1))) uint32_t*)(uintptr_t)g,
        (__attribute__((address_space(3))) uint32_t*)(uintptr_t)l,
        16, 0, 0);
}

// ---------------- prep: weight transposes + bias concat + src/q cvt, ONE dispatch ----------------
__global__ __launch_bounds__(256) void prep(
    const float* __restrict__ s0, const float* __restrict__ s1, const float* __restrict__ s2,
    const float* __restrict__ s3, const float* __restrict__ s4, const float* __restrict__ s5,
    __bf16* __restrict__ d0, __bf16* __restrict__ d1, __bf16* __restrict__ d2,
    __bf16* __restrict__ d3, __bf16* __restrict__ d4, __bf16* __restrict__ d5,
    const float* __restrict__ b_off, const float* __restrict__ b_attn,
    float* __restrict__ bias_oa,
    const float4* __restrict__ src, const float4* __restrict__ pos,
    bf16x4* __restrict__ sb, bf16x4* __restrict__ qb, int n4)
{
    const int tid = threadIdx.x;
    const int b = blockIdx.x;
    if (b >= 737) {   // cvt path
        const int i = (b - 737) * 256 + tid;
        if (i >= n4) return;
        const float4 s = src[i];
        const float4 p = pos[i];
        bf16x4 sv = { (__bf16)s.x, (__bf16)s.y, (__bf16)s.z, (__bf16)s.w };
        bf16x4 qv = { (__bf16)(s.x + p.x), (__bf16)(s.y + p.y),
                      (__bf16)(s.z + p.z), (__bf16)(s.w + p.w) };
        sb[i] = sv;
        qb[i] = qv;
        return;
    }
    if (b == 736) {   // bias concat: [b_off(256) | b_attn(128)]
        if (tid < 256) bias_oa[tid] = b_off[tid];
        if (tid < 128) bias_oa[256 + tid] = b_attn[tid];
        return;
    }
    const int tx = tid & 31;
    const int ty = tid >> 5;
    const int starts[7] = {0, 64, 128, 160, 224, 480, 736};
    const int Ks[6] = {256, 256, 256, 256, 256, 1024};
    const int Ns[6] = {256, 256, 128, 256, 1024, 256};
    const float* srcs[6] = {s0, s1, s2, s3, s4, s5};
    __bf16* dsts[6] = {d0, d1, d2, d3, d4, d5};
    int i = 0;
    while (b >= starts[i + 1]) ++i;
    const int t = b - starts[i];
    const int K = Ks[i], N = Ns[i];
    const float* W = srcs[i];
    __bf16* Wt = dsts[i];
    const int ntx = N >> 5;
    const int n0 = (t % ntx) * 32;
    const int k0 = (t / ntx) * 32;

    __shared__ float tl[32][33];
    #pragma unroll
    for (int j = 0; j < 4; ++j)
        tl[ty + j * 8][tx] = W[(size_t)(k0 + ty + j * 8) * N + n0 + tx];
    __syncthreads();
    #pragma unroll
    for (int j = 0; j < 4; ++j)
        Wt[(size_t)(n0 + ty + j * 8) * K + k0 + tx] = (__bf16)tl[tx][ty + j * 8];
}

// ---------------- bf16 MFMA GEMM core (m97 structure, 128x128 tile, NP=2) ----------------
// C[M,N] = act(A @ Bt^T + bias), bf16 output. Coalesced LDS-assembled epilogue.
// HEADMAJOR: C is [col/32][Mpad][32] planes; stores remapped plane-major so each
// wave writes 1KB contiguous inside one plane (rows adjacent at 64B stride).
template <bool RELU, int K, bool HEADMAJOR>
__device__ __forceinline__ void gemm_core(
    const __bf16* __restrict__ A, const __bf16* __restrict__ Bt,
    const float* __restrict__ bias, __bf16* __restrict__ C,
    int M, int N, int bm, int bn)
{
    // staging: As 2*128*32 (8K elems) + Bs 2*128*32 (8K elems) = 16K elems
    // epilogue: C-tile 128 x 136 = 17408 elems (overlays both)
    __shared__ __bf16 smem[17408];
    __bf16* As = smem;
    __bf16* Bs = smem + 8192;

    const int tid  = threadIdx.x;
    const int lane = tid & 63;
    const int wv   = tid >> 6;
    const int wm   = (wv >> 1) * 64;
    const int wn   = (wv & 1) * 64;
    const int srow = lane >> 2;
    const int skc  = (lane & 3) * 8;
    const int fm   = lane & 15;
    const int fko  = (lane >> 4) * 8;

    f32x4 acc[4][4] = {};

    for (int k0 = 0; k0 < K; k0 += 64) {
        #pragma unroll
        for (int p = 0; p < 2; ++p) {
            #pragma unroll
            for (int c = 0; c < 2; ++c) {
                const int r = wv * 32 + c * 16;
                lds_direct16(A  + (size_t)(bm + r + srow) * K + k0 + p * 32 + skc, As + p * 4096 + r * 32);
                lds_direct16(Bt + (size_t)(bn + r + srow) * K + k0 + p * 32 + skc, Bs + p * 4096 + r * 32);
            }
        }
        __syncthreads();

        #pragma unroll
        for (int p = 0; p < 2; ++p) {
            bf16x8 af[4], bfr[4];
            #pragma unroll
            for (int t = 0; t < 4; ++t) {
                af[t]  = *(const bf16x8*)(As + p * 4096 + (wm + t * 16 + fm) * 32 + fko);
                bfr[t] = *(const bf16x8*)(Bs + p * 4096 + (wn + t * 16 + fm) * 32 + fko);
            }
            #pragma unroll
            for (int mt = 0; mt < 4; ++mt)
                #pragma unroll
                for (int nt = 0; nt < 4; ++nt)
                    acc[mt][nt] = __builtin_amdgcn_mfma_f32_16x16x32_bf16(
                        af[mt], bfr[nt], acc[mt][nt], 0, 0, 0);
        }
        __syncthreads();
    }

    // epilogue: C/D layout col=lane&15, row=(lane>>4)*4+reg [m89-verified]
    // assemble bf16 tile in LDS (stride 136), then coalesced bf16x8 stores.
    const int ecol = lane & 15;
    const int erow = (lane >> 4) * 4;
    #pragma unroll
    for (int nt = 0; nt < 4; ++nt) {
        const int cl = wn + nt * 16 + ecol;
        const float bv = bias[bn + cl];
        #pragma unroll
        for (int mt = 0; mt < 4; ++mt) {
            #pragma unroll
            for (int r = 0; r < 4; ++r) {
                const int rl = wm + mt * 16 + erow + r;
                float v = acc[mt][nt][r] + bv;
                if (RELU) v = fmaxf(v, 0.f);
                smem[rl * 136 + cl] = (__bf16)v;
            }
        }
    }
    __syncthreads();
    #pragma unroll
    for (int rr = 0; rr < 8; ++rr) {
        const int idx = rr * 256 + tid;
        if (HEADMAJOR) {
            const int plane = idx >> 9;          // 4 planes of 32 cols in this 128-col tile
            const int row   = (idx >> 2) & 127;
            const int ch4   = idx & 3;
            if (bm + row < M)
                *(bf16x8*)(C + ((size_t)((bn >> 5) + plane) * M_PAD + (bm + row)) * 32 + ch4 * 8) =
                    *(const bf16x8*)(smem + row * 136 + plane * 32 + ch4 * 8);
        } else {
            const int row = idx >> 4;
            const int ch  = idx & 15;
            if (bm + row < M)
                *(bf16x8*)(C + (size_t)(bm + row) * N + bn + ch * 8) =
                    *(const bf16x8*)(smem + row * 136 + ch * 8);
        }
    }
}

// front GEMM: blocks x<2 -> value (src_b @ Wt_value, head-major), x>=2 -> oa (q_b @ Wt_oa)
__global__ __launch_bounds__(256) void gemm_front(
    const __bf16* __restrict__ A0, const __bf16* __restrict__ B0,
    const float* __restrict__ bi0, __bf16* __restrict__ C0,
    const __bf16* __restrict__ A1, const __bf16* __restrict__ B1,
    const float* __restrict__ bi1, __bf16* __restrict__ C1, int M)
{
    const int bx = blockIdx.x;
    if (bx < 2)
        gemm_core<false, 256, true>(A0, B0, bi0, C0, M, 256, blockIdx.y * 128, bx * 128);
    else
        gemm_core<false, 256, false>(A1, B1, bi1, C1, M, 384, blockIdx.y * 128, (bx - 2) * 128);
}

// FFN1: relu(x_b @ W1 + b1), N=1024
__global__ __launch_bounds__(256) void gemm_ffn1(
    const __bf16* __restrict__ A, const __bf16* __restrict__ Bt,
    const float* __restrict__ bias, __bf16* __restrict__ C, int M)
{
    gemm_core<true, 256, false>(A, Bt, bias, C, M, 1024, blockIdx.y * 128, blockIdx.x * 128);
}

// ---------------- GEMM + residual + LayerNorm fused (64x256 tile, 4 waves) ----------------
// C_ln = LN((A @ Bt^T + bias) + res) * gamma + beta. Wave wv owns cols [wv*64, wv*64+64),
// all 64 rows. 32 MFMA per K-step per wave vs 10 staging loads/thread (2x the 32-row tile).
template <typename OutT, int K>
__global__ __launch_bounds__(256) void gemm_ln64(
    const __bf16* __restrict__ A, const __bf16* __restrict__ Bt,
    const float* __restrict__ bias, const __bf16* __restrict__ res,
    const float* __restrict__ gamma, const float* __restrict__ beta,
    OutT* __restrict__ Cout, int M)
{
    // staging: As 2*64*32 = 4096 elems (8KB), Bs 2*256*32 = 16384 elems (32KB) -> 40KB
    // epilogue overlay: bf16 tile 64x264 = 16896 elems (33.8KB); fp32 half-tile 32x260 (33.3KB)
    __shared__ __bf16 smem[20480];
    __bf16* As = smem;
    __bf16* Bs = smem + 4096;
    __shared__ float lnsum[64][4];
    __shared__ float lnsq[64][4];
    __shared__ float lnstat[64][2];

    const int tid  = threadIdx.x;
    const int lane = tid & 63;
    const int wv   = tid >> 6;
    const int bm   = blockIdx.x * 64;
    const int wn   = wv * 64;
    const int srow = lane >> 2;
    const int skc  = (lane & 3) * 8;
    const int fm   = lane & 15;
    const int fko  = (lane >> 4) * 8;

    f32x4 acc[4][4] = {};

    for (int k0 = 0; k0 < K; k0 += 64) {
        // A staging: 2 panels x 64 rows; wave covers 16 rows/panel -> 2 loads/thread
        #pragma unroll
        for (int p = 0; p < 2; ++p) {
            const int r = wv * 16;
            lds_direct16(A + (size_t)(bm + r + srow) * K + k0 + p * 32 + skc,
                         As + p * 2048 + r * 32);
        }
        // B staging: full 256 rows, both panels -> 8 loads/thread
        #pragma unroll
        for (int p = 0; p < 2; ++p) {
            #pragma unroll
            for (int c = 0; c < 4; ++c) {
                const int r = wv * 64 + c * 16;
                lds_direct16(Bt + (size_t)(r + srow) * K + k0 + p * 32 + skc,
                             Bs + p * 8192 + r * 32);
            }
        }
        __syncthreads();

        #pragma unroll
        for (int p = 0; p < 2; ++p) {
            bf16x8 af[4], bfr[4];
            #pragma unroll
            for (int mt = 0; mt < 4; ++mt)
                af[mt] = *(const bf16x8*)(As + p * 2048 + (mt * 16 + fm) * 32 + fko);
            #pragma unroll
            for (int nt = 0; nt < 4; ++nt)
                bfr[nt] = *(const bf16x8*)(Bs + p * 8192 + (wn + nt * 16 + fm) * 32 + fko);
            #pragma unroll
            for (int mt = 0; mt < 4; ++mt)
                #pragma unroll
                for (int nt = 0; nt < 4; ++nt)
                    acc[mt][nt] = __builtin_amdgcn_mfma_f32_16x16x32_bf16(
                        af[mt], bfr[nt], acc[mt][nt], 0, 0, 0);
        }
        __syncthreads();
    }

    const int ecol = lane & 15;
    const int erow = (lane >> 4) * 4;

    // bias + residual
    float g4[4], b4[4];
    #pragma unroll
    for (int nt = 0; nt < 4; ++nt) {
        const int col = wn + nt * 16 + ecol;
        g4[nt] = gamma[col];
        b4[nt] = beta[col];
        const float bv = bias[col];
        #pragma unroll
        for (int mt = 0; mt < 4; ++mt) {
            #pragma unroll
            for (int r = 0; r < 4; ++r) {
                const int row = bm + mt * 16 + erow + r;
                acc[mt][nt][r] += bv + (float)res[(size_t)row * 256 + col];
            }
        }
    }

    // per-row sums (wave's 64-col slice), 16-lane shuffle reduce
    #pragma unroll
    for (int mt = 0; mt < 4; ++mt) {
        #pragma unroll
        for (int r = 0; r < 4; ++r) {
            float s  = acc[mt][0][r] + acc[mt][1][r] + acc[mt][2][r] + acc[mt][3][r];
            float s2 = acc[mt][0][r] * acc[mt][0][r] + acc[mt][1][r] * acc[mt][1][r]
                     + acc[mt][2][r] * acc[mt][2][r] + acc[mt][3][r] * acc[mt][3][r];
            #pragma unroll
            for (int o = 1; o < 16; o <<= 1) {
                s  += __shfl_xor(s, o);
                s2 += __shfl_xor(s2, o);
            }
            if (ecol == 0) {
                const int rl = mt * 16 + erow + r;
                lnsum[rl][wv] = s;
                lnsq[rl][wv]  = s2;
            }
        }
    }
    __syncthreads();
    if (tid < 64) {
        const float s  = lnsum[tid][0] + lnsum[tid][1] + lnsum[tid][2] + lnsum[tid][3];
        const float s2 = lnsq[tid][0] + lnsq[tid][1] + lnsq[tid][2] + lnsq[tid][3];
        const float mu = s * (1.f / 256.f);
        const float var = s2 * (1.f / 256.f) - mu * mu;
        lnstat[tid][0] = mu;
        lnstat[tid][1] = rsqrtf(var + 1e-5f);
    }
    __syncthreads();

    // normalize into LDS tile, then coalesced stores
    if constexpr (sizeof(OutT) == 2) {
        __bf16* ct = smem;   // [64][264]
        #pragma unroll
        for (int mt = 0; mt < 4; ++mt) {
            #pragma unroll
            for (int r = 0; r < 4; ++r) {
                const int rl = mt * 16 + erow + r;
                const float mu = lnstat[rl][0];
                const float rs = lnstat[rl][1];
                #pragma unroll
                for (int nt = 0; nt < 4; ++nt) {
                    const int col = wn + nt * 16 + ecol;
                    ct[rl * 264 + col] = (__bf16)((acc[mt][nt][r] - mu) * rs * g4[nt] + b4[nt]);
                }
            }
        }
        __syncthreads();
        #pragma unroll
        for (int rr = 0; rr < 8; ++rr) {
            const int idx = rr * 256 + tid;
            const int row = idx >> 5;
            const int ch  = idx & 31;
            if (bm + row < M)
                *(bf16x8*)((__bf16*)Cout + (size_t)(bm + row) * 256 + ch * 8) =
                    *(const bf16x8*)(ct + row * 264 + ch * 8);
        }
    } else {
        float* ct = (float*)smem;   // [32][260] per half
        #pragma unroll
        for (int hf = 0; hf < 2; ++hf) {
            #pragma unroll
            for (int mt2 = 0; mt2 < 2; ++mt2) {
                const int mt = hf * 2 + mt2;
                #pragma unroll
                for (int r = 0; r < 4; ++r) {
                    const int rl   = mt * 16 + erow + r;
                    const int rloc = rl - hf * 32;
                    const float mu = lnstat[rl][0];
                    const float rs = lnstat[rl][1];
                    #pragma unroll
                    for (int nt = 0; nt < 4; ++nt) {
                        const int col = wn + nt * 16 + ecol;
                        ct[rloc * 260 + col] = (acc[mt][nt][r] - mu) * rs * g4[nt] + b4[nt];
                    }
                }
            }
            __syncthreads();
            #pragma unroll
            for (int rr = 0; rr < 8; ++rr) {
                const int idx = rr * 256 + tid;
                const int row = idx >> 6;
                const int ch  = idx & 63;
                const int grow = bm + hf * 32 + row;
                if (grow < M) {
                    float4 v = *(const float4*)(ct + row * 260 + ch * 4);
                    *(float4*)((float*)Cout + (size_t)grow * 256 + ch * 4) = v;
                }
            }
            if (hf == 0) __syncthreads();
        }
    }
}

// ---------------- deformable sampling ----------------
// value is HEAD-MAJOR: [8][Mpad][32] bf16, so corner x-pairs are 128B contiguous.
// 4 tokens per block, 256 thr = 4 tok x 8 heads x 8 lanes; per (q,dy) each lane
// loads dwordx4 of a 128B window covering BOTH x-corners (lanes 0-3: xs row,
// 4-7: xs+1 row). shfl_xor(4) folds the halves at the end.
__global__ __launch_bounds__(256) void msda_sample(
    const __bf16* __restrict__ value, // [8][Mpad][32] bf16, head-major planes
    const __bf16* __restrict__ oa,    // [Mpad, 384] bf16: [off(256) | attn(128)]
    const float* __restrict__ refp,   // [M, 4, 2]
    __bf16* __restrict__ out)         // [Mpad, 256] bf16
{
    __shared__ uint32_t sc[32 * 132]; // per (t,h): 16q x 2dy x {boff,w0,w1,pad} ; 16.9 KB
    __shared__ float sw[32][16];      // softmax weights ; 2 KB

    const int tid = threadIdx.x;
    const int blk = blockIdx.x;

    // ---- phase 1: softmax, one (token,head) per thread (32 threads)
    if (tid < 32) {
        const int t = tid >> 3;
        const int h = tid & 7;
        const int row = blk * 4 + t;
        const __bf16* ap = oa + (size_t)row * 384 + 256 + h * 16;
        const bf16x8 v0 = *(const bf16x8*)ap;
        const bf16x8 v1 = *(const bf16x8*)(ap + 8);
        float e[16];
        #pragma unroll
        for (int i = 0; i < 8; ++i) { e[i] = (float)v0[i]; e[8 + i] = (float)v1[i]; }
        float mx = -1e30f;
        #pragma unroll
        for (int i = 0; i < 16; ++i) mx = fmaxf(mx, e[i]);
        float s = 0.f;
        #pragma unroll
        for (int i = 0; i < 16; ++i) { e[i] = __expf(e[i] - mx); s += e[i]; }
        const float inv = 1.f / s;
        #pragma unroll
        for (int i = 0; i < 16; ++i) sw[tid][i] = e[i] * inv;
    }
    __syncthreads();

    // ---- phase 2: per (t,h,lp): two x-pair entries (dy=0,1), 2 items per thread
    #pragma unroll
    for (int it = 0; it < 2; ++it) {
        const int idx = it * 256 + tid;       // 0..511 = t*128 + h*16 + lp
        const int t  = idx >> 7;
        const int h  = (idx >> 4) & 7;
        const int lp = idx & 15;
        const int l  = lp >> 2;
        const int row = blk * 4 + t;
        const int Ww = c_lvl_w[l];
        const int Hh = c_lvl_h[l];
        const uint32_t opk = *(const uint32_t*)(oa + (size_t)row * 384 + h * 32 + lp * 2);
        const float ox = bflo(opk), oy = bfhi(opk);
        const float rx = refp[((size_t)row * 4 + l) * 2 + 0];
        const float ry = refp[((size_t)row * 4 + l) * 2 + 1];
        const float x = (rx + ox / (float)Ww) * (float)Ww - 0.5f;
        const float y = (ry + oy / (float)Hh) * (float)Hh - 0.5f;
        const float xf = floorf(x), yf = floorf(y);
        const float fx = x - xf,    fy = y - yf;
        const int x0 = (int)xf, y0 = (int)yf;
        const int n  = (row >= LEN_IN) ? 1 : 0;
        const int lvlbase = n * LEN_IN + c_lvl_s[l];
        const float a = sw[t * 8 + h][lp];
        // x window: xs = clamp(x0, 0, W-2); loaded positions xs, xs+1
        const int xs = min(max(x0, 0), Ww - 2);
        const int d  = x0 - xs;   // -1: only right corner (at xs); 0: both; 1: only left (at xs+1)
        const float wxl = 1.f - fx, wxr = fx;
        const float pw0 = (d == 0) ? wxl : ((d == -1) ? wxr : 0.f);
        const float pw1 = (d == 0) ? wxr : ((d == 1) ? wxl : 0.f);
        uint32_t* p = sc + (t * 8 + h) * 132 + lp * 8;
        #pragma unroll
        for (int dy = 0; dy < 2; ++dy) {
            const int yi = y0 + dy;
            const int yc = min(max(yi, 0), Hh - 1);
            const bool yv = (yi >= 0) & (yi < Hh);
            const float wy = (dy ? fy : 1.f - fy) * (yv ? a : 0.f);
            const uint32_t boff = (uint32_t)(lvlbase + yc * Ww + xs) * 64u;  // BYTE offset in plane
            u32x4 pk = { boff, __float_as_uint(pw0 * wy), __float_as_uint(pw1 * wy), 0u };
            *(u32x4*)(p + dy * 4) = pk;
        }
    }
    __syncthreads();

    // ---- phase 3: gather. wave = 1 token; lane = (h, c8); c8<4 -> xs row, c8>=4 -> xs+1 row
    const int t  = tid >> 6;
    const int h  = (tid >> 3) & 7;
    const int c8 = tid & 7;
    const uint32_t* mb = sc + (t * 8 + h) * 132;
    const char* __restrict__ vpb = (const char*)(value + (size_t)h * (M_PAD * 32));
    const uint32_t lsub = (uint32_t)c8 * 16u;
    const bool hi = (c8 >= 4);
    float acc[8] = {};
    #pragma unroll 8
    for (int qd = 0; qd < 32; ++qd) {
        const u32x4 md = *(const u32x4*)(mb + qd * 4);
        const float w = __uint_as_float(hi ? md.z : md.y);
        const u32x4 v = *(const u32x4*)(vpb + (size_t)(md.x + lsub));
        #pragma unroll
        for (int d2 = 0; d2 < 4; ++d2) {
            acc[2 * d2]     += w * bflo(v[d2]);
            acc[2 * d2 + 1] += w * bfhi(v[d2]);
        }
    }
    #pragma unroll
    for (int j = 0; j < 8; ++j) acc[j] += __shfl_xor(acc[j], 4);
    if (c8 < 4) {
        bf16x8 o;
        #pragma unroll
        for (int j = 0; j < 8; ++j) o[j] = (__bf16)acc[j];
        const int orow = blk * 4 + t;
        *(bf16x8*)(out + (size_t)orow * 256 + h * 32 + c8 * 8) = o;
    }
}

// ---------------- launch ----------------
extern "C" void kernel_launch(void* const* d_in, const int* in_sizes, int n_in,
                              void* d_out, int out_size, void* d_ws, size_t ws_size,
                              hipStream_t stream)
{
    const float* src     = (const float*)d_in[0];
    const float* pos     = (const float*)d_in[1];
    const float* refp    = (const float*)d_in[2];
    const float* W_value = (const float*)d_in[5];
    const float* b_value = (const float*)d_in[6];
    const float* W_off   = (const float*)d_in[7];
    const float* b_off   = (const float*)d_in[8];
    const float* W_attn  = (const float*)d_in[9];
    const float* b_attn  = (const float*)d_in[10];
    const float* W_out   = (const float*)d_in[11];
    const float* b_out   = (const float*)d_in[12];
    const float* W1      = (const float*)d_in[13];
    const float* b1      = (const float*)d_in[14];
    const float* W2      = (const float*)d_in[15];
    const float* b2      = (const float*)d_in[16];
    const float* g1      = (const float*)d_in[17];
    const float* be1     = (const float*)d_in[18];
    const float* g2      = (const float*)d_in[19];
    const float* be2     = (const float*)d_in[20];
    float* outp = (float*)d_out;

    const int M = M_TOK;
    char* ws = (char*)d_ws;
    const size_t R2 = (size_t)M_PAD * 512;   // bytes of one [Mpad,256] bf16 buffer

    __bf16* src_b = (__bf16*)(ws);                    // [0, R2)
    __bf16* q_b   = (__bf16*)(ws + R2);               // [R2, 2R2)
    __bf16* val_b = (__bf16*)(ws + 2 * R2);           // [2R2, 3R2)  head-major [8][Mpad][32]
    __bf16* oa    = (__bf16*)(ws + 3 * R2);           // [3R2, 4.5R2)
    __bf16* samp  = (__bf16*)(ws + 9 * R2 / 2);       // [4.5R2, 5.5R2)
    __bf16* x_b   = (__bf16*)(ws + 11 * R2 / 2);      // [5.5R2, 6.5R2)
    __bf16* hbuf  = (__bf16*)(ws);                    // [0, 4R2) overlay (dead by FFN1)
    __bf16* wbase = (__bf16*)(ws + 13 * R2 / 2);
    __bf16* Wt_value = wbase;                          // [256][256]
    __bf16* Wt_oa    = wbase + 65536;                  // [384][256]
    __bf16* Wt_out   = wbase + 163840;                 // [256][256]
    __bf16* Wt1      = wbase + 229376;                 // [1024][256]
    __bf16* Wt2      = wbase + 491520;                 // [256][1024]
    float*  bias_oa  = (float*)(wbase + 753664);       // [384]

    const dim3 blk(256);
    const int n4 = M * 256 / 4;
    const int gm = M_PAD / 128;  // 208

    prep<<<dim3(737 + (n4 + 255) / 256), blk, 0, stream>>>(
        W_value, W_off, W_attn, W_out, W1, W2,
        Wt_value, Wt_oa, Wt_oa + 65536, Wt_out, Wt1, Wt2,
        b_off, b_attn, bias_oa,
        (const float4*)src, (const float4*)pos, (bf16x4*)src_b, (bf16x4*)q_b, n4);

    // value (2 n-tiles, head-major) + oa (3 n-tiles): 5 x 208 = 1040 blocks
    gemm_front<<<dim3(5, gm), blk, 0, stream>>>(
        src_b, Wt_value, b_value, val_b,
        q_b,   Wt_oa,    bias_oa, oa, M);

    msda_sample<<<dim3(M / 4), blk, 0, stream>>>(val_b, oa, refp, samp);

    // x_b = LN(src + samp @ W_out + b_out)  (bf16), 64-row blocks
    gemm_ln64<__bf16, 256><<<dim3(M_PAD / 64), blk, 0, stream>>>(
        samp, Wt_out, b_out, src_b, g1, be1, x_b, M);

    // hbuf = relu(x_b @ W1 + b1)
    gemm_ffn1<<<dim3(8, gm), blk, 0, stream>>>(x_b, Wt1, b1, hbuf, M);

    // out = LN(x_b + hbuf @ W2 + b2)  (fp32, to d_out), 64-row blocks
    gemm_ln64<float, 1024><<<dim3(M_PAD / 64), blk, 0, stream>>>(
        hbuf, Wt2, b2, x_b, g2, be2, outp, M);
}

// Round 4
// 301.738 us; speedup vs baseline: 1.0290x; 1.0290x over previous
//
#include <hip/hip_runtime.h>
#include <hip/hip_bf16.h>
#include <cstdint>

// ---------------- static problem config ----------------
#define D_MODEL   256
#define N_HEADS   8
#define N_LEVELS  4
#define N_POINTS  4
#define D_FFN     1024
#define D_HEAD    32
#define LEN_IN    13294          // 100*100 + 50*50 + 25*25 + 13*13
#define NBATCH    2
#define M_TOK     (NBATCH * LEN_IN)   // 26588
#define M_PAD     26624               // 208*128 = 416*64 = 832*32

__constant__ int c_lvl_h[4] = {100, 50, 25, 13};
__constant__ int c_lvl_w[4] = {100, 50, 25, 13};
__constant__ int c_lvl_s[4] = {0, 10000, 12500, 13125};

typedef __attribute__((ext_vector_type(8))) __bf16 bf16x8;
typedef __attribute__((ext_vector_type(4))) __bf16 bf16x4;
typedef __attribute__((ext_vector_type(4))) float  f32x4;
typedef __attribute__((ext_vector_type(4))) uint32_t u32x4;

__device__ __forceinline__ float bflo(uint32_t w) { return __uint_as_float(w << 16); }
__device__ __forceinline__ float bfhi(uint32_t w) { return __uint_as_float(w & 0xffff0000u); }

// async global->LDS, 16B per lane; lds base wave-uniform (lane i lands at base + i*16)
__device__ __forceinline__ void lds_direct16(const void* g, void* l) {
    __builtin_amdgcn_global_load_lds(
        (const __attribute__((address_space(1))) uint32_t*)(uintptr_t)g,
        (__attribute__((address_space(3))) uint32_t*)(uintptr_t)l,
        16, 0, 0);
}

// ---------------- prep: weight transposes + bias concat + src/q cvt, ONE dispatch ----------------
__global__ __launch_bounds__(256) void prep(
    const float* __restrict__ s0, const float* __restrict__ s1, const float* __restrict__ s2,
    const float* __restrict__ s3, const float* __restrict__ s4, const float* __restrict__ s5,
    __bf16* __restrict__ d0, __bf16* __restrict__ d1, __bf16* __restrict__ d2,
    __bf16* __restrict__ d3, __bf16* __restrict__ d4, __bf16* __restrict__ d5,
    const float* __restrict__ b_off, const float* __restrict__ b_attn,
    float* __restrict__ bias_oa,
    const float4* __restrict__ src, const float4* __restrict__ pos,
    bf16x4* __restrict__ sb, bf16x4* __restrict__ qb, int n4)
{
    const int tid = threadIdx.x;
    const int b = blockIdx.x;
    if (b >= 737) {   // cvt path
        const int i = (b - 737) * 256 + tid;
        if (i >= n4) return;
        const float4 s = src[i];
        const float4 p = pos[i];
        bf16x4 sv = { (__bf16)s.x, (__bf16)s.y, (__bf16)s.z, (__bf16)s.w };
        bf16x4 qv = { (__bf16)(s.x + p.x), (__bf16)(s.y + p.y),
                      (__bf16)(s.z + p.z), (__bf16)(s.w + p.w) };
        sb[i] = sv;
        qb[i] = qv;
        return;
    }
    if (b == 736) {   // bias concat: [b_off(256) | b_attn(128)]
        if (tid < 256) bias_oa[tid] = b_off[tid];
        if (tid < 128) bias_oa[256 + tid] = b_attn[tid];
        return;
    }
    const int tx = tid & 31;
    const int ty = tid >> 5;
    const int starts[7] = {0, 64, 128, 160, 224, 480, 736};
    const int Ks[6] = {256, 256, 256, 256, 256, 1024};
    const int Ns[6] = {256, 256, 128, 256, 1024, 256};
    const float* srcs[6] = {s0, s1, s2, s3, s4, s5};
    __bf16* dsts[6] = {d0, d1, d2, d3, d4, d5};
    int i = 0;
    while (b >= starts[i + 1]) ++i;
    const int t = b - starts[i];
    const int K = Ks[i], N = Ns[i];
    const float* W = srcs[i];
    __bf16* Wt = dsts[i];
    const int ntx = N >> 5;
    const int n0 = (t % ntx) * 32;
    const int k0 = (t / ntx) * 32;

    __shared__ float tl[32][33];
    #pragma unroll
    for (int j = 0; j < 4; ++j)
        tl[ty + j * 8][tx] = W[(size_t)(k0 + ty + j * 8) * N + n0 + tx];
    __syncthreads();
    #pragma unroll
    for (int j = 0; j < 4; ++j)
        Wt[(size_t)(n0 + ty + j * 8) * K + k0 + tx] = (__bf16)tl[tx][ty + j * 8];
}

// ---------------- bf16 MFMA GEMM core (m97 structure, 128x128 tile, NP=2) ----------------
// C[M,N] = act(A @ Bt^T + bias), bf16 output. Coalesced LDS-assembled epilogue.
// HEADMAJOR: C is [col/32][Mpad][32] planes; stores remapped plane-major so each
// wave writes 1KB contiguous inside one plane (rows adjacent at 64B stride).
template <bool RELU, int K, bool HEADMAJOR>
__device__ __forceinline__ void gemm_core(
    const __bf16* __restrict__ A, const __bf16* __restrict__ Bt,
    const float* __restrict__ bias, __bf16* __restrict__ C,
    int M, int N, int bm, int bn)
{
    // staging: As 2*128*32 (8K elems) + Bs 2*128*32 (8K elems) = 16K elems
    // epilogue: C-tile 128 x 136 = 17408 elems (overlays both)
    __shared__ __bf16 smem[17408];
    __bf16* As = smem;
    __bf16* Bs = smem + 8192;

    const int tid  = threadIdx.x;
    const int lane = tid & 63;
    const int wv   = tid >> 6;
    const int wm   = (wv >> 1) * 64;
    const int wn   = (wv & 1) * 64;
    const int srow = lane >> 2;
    const int skc  = (lane & 3) * 8;
    const int fm   = lane & 15;
    const int fko  = (lane >> 4) * 8;

    f32x4 acc[4][4] = {};

    for (int k0 = 0; k0 < K; k0 += 64) {
        #pragma unroll
        for (int p = 0; p < 2; ++p) {
            #pragma unroll
            for (int c = 0; c < 2; ++c) {
                const int r = wv * 32 + c * 16;
                lds_direct16(A  + (size_t)(bm + r + srow) * K + k0 + p * 32 + skc, As + p * 4096 + r * 32);
                lds_direct16(Bt + (size_t)(bn + r + srow) * K + k0 + p * 32 + skc, Bs + p * 4096 + r * 32);
            }
        }
        __syncthreads();

        #pragma unroll
        for (int p = 0; p < 2; ++p) {
            bf16x8 af[4], bfr[4];
            #pragma unroll
            for (int t = 0; t < 4; ++t) {
                af[t]  = *(const bf16x8*)(As + p * 4096 + (wm + t * 16 + fm) * 32 + fko);
                bfr[t] = *(const bf16x8*)(Bs + p * 4096 + (wn + t * 16 + fm) * 32 + fko);
            }
            #pragma unroll
            for (int mt = 0; mt < 4; ++mt)
                #pragma unroll
                for (int nt = 0; nt < 4; ++nt)
                    acc[mt][nt] = __builtin_amdgcn_mfma_f32_16x16x32_bf16(
                        af[mt], bfr[nt], acc[mt][nt], 0, 0, 0);
        }
        __syncthreads();
    }

    // epilogue: C/D layout col=lane&15, row=(lane>>4)*4+reg [m89-verified]
    // assemble bf16 tile in LDS (stride 136), then coalesced bf16x8 stores.
    const int ecol = lane & 15;
    const int erow = (lane >> 4) * 4;
    #pragma unroll
    for (int nt = 0; nt < 4; ++nt) {
        const int cl = wn + nt * 16 + ecol;
        const float bv = bias[bn + cl];
        #pragma unroll
        for (int mt = 0; mt < 4; ++mt) {
            #pragma unroll
            for (int r = 0; r < 4; ++r) {
                const int rl = wm + mt * 16 + erow + r;
                float v = acc[mt][nt][r] + bv;
                if (RELU) v = fmaxf(v, 0.f);
                smem[rl * 136 + cl] = (__bf16)v;
            }
        }
    }
    __syncthreads();
    #pragma unroll
    for (int rr = 0; rr < 8; ++rr) {
        const int idx = rr * 256 + tid;
        if (HEADMAJOR) {
            const int plane = idx >> 9;          // 4 planes of 32 cols in this 128-col tile
            const int row   = (idx >> 2) & 127;
            const int ch4   = idx & 3;
            if (bm + row < M)
                *(bf16x8*)(C + ((size_t)((bn >> 5) + plane) * M_PAD + (bm + row)) * 32 + ch4 * 8) =
                    *(const bf16x8*)(smem + row * 136 + plane * 32 + ch4 * 8);
        } else {
            const int row = idx >> 4;
            const int ch  = idx & 15;
            if (bm + row < M)
                *(bf16x8*)(C + (size_t)(bm + row) * N + bn + ch * 8) =
                    *(const bf16x8*)(smem + row * 136 + ch * 8);
        }
    }
}

// front GEMM: blocks x<2 -> value (src_b @ Wt_value, head-major), x>=2 -> oa (q_b @ Wt_oa)
__global__ __launch_bounds__(256) void gemm_front(
    const __bf16* __restrict__ A0, const __bf16* __restrict__ B0,
    const float* __restrict__ bi0, __bf16* __restrict__ C0,
    const __bf16* __restrict__ A1, const __bf16* __restrict__ B1,
    const float* __restrict__ bi1, __bf16* __restrict__ C1, int M)
{
    const int bx = blockIdx.x;
    if (bx < 2)
        gemm_core<false, 256, true>(A0, B0, bi0, C0, M, 256, blockIdx.y * 128, bx * 128);
    else
        gemm_core<false, 256, false>(A1, B1, bi1, C1, M, 384, blockIdx.y * 128, (bx - 2) * 128);
}

// FFN1: relu(x_b @ W1 + b1), N=1024
__global__ __launch_bounds__(256) void gemm_ffn1(
    const __bf16* __restrict__ A, const __bf16* __restrict__ Bt,
    const float* __restrict__ bias, __bf16* __restrict__ C, int M)
{
    gemm_core<true, 256, false>(A, Bt, bias, C, M, 1024, blockIdx.y * 128, blockIdx.x * 128);
}

// ---------------- GEMM + residual + LayerNorm fused (32x256 tile, BK=32, 4 waves) ----------------
// Occupancy-first: ~19.7KB LDS, launch_bounds(256,5) -> 5 blocks/CU, 832-block grid
// fully co-resident. Wave wv owns cols [wv*64, wv*64+64). 8 MFMA per K-step per wave.
template <typename OutT, int K>
__global__ __launch_bounds__(256, 5) void gemm_ln(
    const __bf16* __restrict__ A, const __bf16* __restrict__ Bt,
    const float* __restrict__ bias, const __bf16* __restrict__ res,
    const float* __restrict__ gamma, const float* __restrict__ beta,
    OutT* __restrict__ Cout, int M)
{
    // staging: As 32*32 = 1024 elems (2KB), Bs 256*32 = 8192 elems (16KB) -> 18KB
    // epilogue overlay: bf16 tile 32x264 = 16.9KB; fp32 half-tile 16x260 = 16.6KB
    __shared__ __bf16 smem[9216];
    __bf16* As = smem;           // [32][32]
    __bf16* Bs = smem + 1024;    // [256][32]
    __shared__ float lnsum[32][4];
    __shared__ float lnsq[32][4];
    __shared__ float lnstat[32][2];

    const int tid  = threadIdx.x;
    const int lane = tid & 63;
    const int wv   = tid >> 6;
    const int bm   = blockIdx.x * 32;
    const int wn   = wv * 64;
    const int srow = lane >> 2;
    const int skc  = (lane & 3) * 8;
    const int fm   = lane & 15;
    const int fko  = (lane >> 4) * 8;

    f32x4 acc[2][4] = {};

    for (int k0 = 0; k0 < K; k0 += 32) {
        // A staging: 32 rows x 32 cols = 128 chunks; threads 0-127 (waves 0,1)
        if (tid < 128)
            lds_direct16(A + (size_t)(bm + (tid >> 2)) * K + k0 + (tid & 3) * 8,
                         As + tid * 8);
        // B staging: 256 rows x 32 cols; each wave covers 64 rows (4 x 16-row chunks)
        #pragma unroll
        for (int c = 0; c < 4; ++c) {
            const int r = wv * 64 + c * 16;
            lds_direct16(Bt + (size_t)(r + srow) * K + k0 + skc, Bs + r * 32);
        }
        __syncthreads();

        bf16x8 af[2], bfr[4];
        #pragma unroll
        for (int mt = 0; mt < 2; ++mt)
            af[mt] = *(const bf16x8*)(As + (mt * 16 + fm) * 32 + fko);
        #pragma unroll
        for (int nt = 0; nt < 4; ++nt)
            bfr[nt] = *(const bf16x8*)(Bs + (wn + nt * 16 + fm) * 32 + fko);
        #pragma unroll
        for (int mt = 0; mt < 2; ++mt)
            #pragma unroll
            for (int nt = 0; nt < 4; ++nt)
                acc[mt][nt] = __builtin_amdgcn_mfma_f32_16x16x32_bf16(
                    af[mt], bfr[nt], acc[mt][nt], 0, 0, 0);
        __syncthreads();
    }

    const int ecol = lane & 15;
    const int erow = (lane >> 4) * 4;

    // bias + residual
    float g4[4], b4[4];
    #pragma unroll
    for (int nt = 0; nt < 4; ++nt) {
        const int col = wn + nt * 16 + ecol;
        g4[nt] = gamma[col];
        b4[nt] = beta[col];
        const float bv = bias[col];
        #pragma unroll
        for (int mt = 0; mt < 2; ++mt) {
            #pragma unroll
            for (int r = 0; r < 4; ++r) {
                const int row = bm + mt * 16 + erow + r;
                acc[mt][nt][r] += bv + (float)res[(size_t)row * 256 + col];
            }
        }
    }

    // per-row sums (wave's 64-col slice), 16-lane shuffle reduce
    #pragma unroll
    for (int mt = 0; mt < 2; ++mt) {
        #pragma unroll
        for (int r = 0; r < 4; ++r) {
            float s  = acc[mt][0][r] + acc[mt][1][r] + acc[mt][2][r] + acc[mt][3][r];
            float s2 = acc[mt][0][r] * acc[mt][0][r] + acc[mt][1][r] * acc[mt][1][r]
                     + acc[mt][2][r] * acc[mt][2][r] + acc[mt][3][r] * acc[mt][3][r];
            #pragma unroll
            for (int o = 1; o < 16; o <<= 1) {
                s  += __shfl_xor(s, o);
                s2 += __shfl_xor(s2, o);
            }
            if (ecol == 0) {
                const int rl = mt * 16 + erow + r;
                lnsum[rl][wv] = s;
                lnsq[rl][wv]  = s2;
            }
        }
    }
    __syncthreads();
    if (tid < 32) {
        const float s  = lnsum[tid][0] + lnsum[tid][1] + lnsum[tid][2] + lnsum[tid][3];
        const float s2 = lnsq[tid][0] + lnsq[tid][1] + lnsq[tid][2] + lnsq[tid][3];
        const float mu = s * (1.f / 256.f);
        const float var = s2 * (1.f / 256.f) - mu * mu;
        lnstat[tid][0] = mu;
        lnstat[tid][1] = rsqrtf(var + 1e-5f);
    }
    __syncthreads();

    // normalize into LDS tile, then coalesced stores
    if constexpr (sizeof(OutT) == 2) {
        __bf16* ct = smem;   // [32][264]
        #pragma unroll
        for (int mt = 0; mt < 2; ++mt) {
            #pragma unroll
            for (int r = 0; r < 4; ++r) {
                const int rl = mt * 16 + erow + r;
                const float mu = lnstat[rl][0];
                const float rs = lnstat[rl][1];
                #pragma unroll
                for (int nt = 0; nt < 4; ++nt) {
                    const int col = wn + nt * 16 + ecol;
                    ct[rl * 264 + col] = (__bf16)((acc[mt][nt][r] - mu) * rs * g4[nt] + b4[nt]);
                }
            }
        }
        __syncthreads();
        #pragma unroll
        for (int rr = 0; rr < 4; ++rr) {
            const int idx = rr * 256 + tid;
            const int row = idx >> 5;
            const int ch  = idx & 31;
            if (bm + row < M)
                *(bf16x8*)((__bf16*)Cout + (size_t)(bm + row) * 256 + ch * 8) =
                    *(const bf16x8*)(ct + row * 264 + ch * 8);
        }
    } else {
        float* ct = (float*)smem;   // [16][260] per half
        #pragma unroll
        for (int hf = 0; hf < 2; ++hf) {
            const int mt = hf;
            #pragma unroll
            for (int r = 0; r < 4; ++r) {
                const int rl   = mt * 16 + erow + r;
                const int rloc = erow + r;
                const float mu = lnstat[rl][0];
                const float rs = lnstat[rl][1];
                #pragma unroll
                for (int nt = 0; nt < 4; ++nt) {
                    const int col = wn + nt * 16 + ecol;
                    ct[rloc * 260 + col] = (acc[mt][nt][r] - mu) * rs * g4[nt] + b4[nt];
                }
            }
            __syncthreads();
            #pragma unroll
            for (int rr = 0; rr < 4; ++rr) {
                const int idx = rr * 256 + tid;
                const int row = idx >> 6;
                const int ch  = idx & 63;
                const int grow = bm + hf * 16 + row;
                if (grow < M) {
                    float4 v = *(const float4*)(ct + row * 260 + ch * 4);
                    *(float4*)((float*)Cout + (size_t)grow * 256 + ch * 4) = v;
                }
            }
            __syncthreads();
        }
    }
}

// ---------------- deformable sampling ----------------
// value is HEAD-MAJOR: [8][Mpad][32] bf16, so corner x-pairs are 128B contiguous.
// 4 tokens per block, 256 thr = 4 tok x 8 heads x 8 lanes; per (q,dy) each lane
// loads dwordx4 of a 128B window covering BOTH x-corners (lanes 0-3: xs row,
// 4-7: xs+1 row). shfl_xor(4) folds the halves at the end.
__global__ __launch_bounds__(256) void msda_sample(
    const __bf16* __restrict__ value, // [8][Mpad][32] bf16, head-major planes
    const __bf16* __restrict__ oa,    // [Mpad, 384] bf16: [off(256) | attn(128)]
    const float* __restrict__ refp,   // [M, 4, 2]
    __bf16* __restrict__ out)         // [Mpad, 256] bf16
{
    __shared__ uint32_t sc[32 * 132]; // per (t,h): 16q x 2dy x {boff,w0,w1,pad} ; 16.9 KB
    __shared__ float sw[32][16];      // softmax weights ; 2 KB

    const int tid = threadIdx.x;
    const int blk = blockIdx.x;

    // ---- phase 1: softmax, one (token,head) per thread (32 threads)
    if (tid < 32) {
        const int t = tid >> 3;
        const int h = tid & 7;
        const int row = blk * 4 + t;
        const __bf16* ap = oa + (size_t)row * 384 + 256 + h * 16;
        const bf16x8 v0 = *(const bf16x8*)ap;
        const bf16x8 v1 = *(const bf16x8*)(ap + 8);
        float e[16];
        #pragma unroll
        for (int i = 0; i < 8; ++i) { e[i] = (float)v0[i]; e[8 + i] = (float)v1[i]; }
        float mx = -1e30f;
        #pragma unroll
        for (int i = 0; i < 16; ++i) mx = fmaxf(mx, e[i]);
        float s = 0.f;
        #pragma unroll
        for (int i = 0; i < 16; ++i) { e[i] = __expf(e[i] - mx); s += e[i]; }
        const float inv = 1.f / s;
        #pragma unroll
        for (int i = 0; i < 16; ++i) sw[tid][i] = e[i] * inv;
    }
    __syncthreads();

    // ---- phase 2: per (t,h,lp): two x-pair entries (dy=0,1), 2 items per thread
    #pragma unroll
    for (int it = 0; it < 2; ++it) {
        const int idx = it * 256 + tid;       // 0..511 = t*128 + h*16 + lp
        const int t  = idx >> 7;
        const int h  = (idx >> 4) & 7;
        const int lp = idx & 15;
        const int l  = lp >> 2;
        const int row = blk * 4 + t;
        const int Ww = c_lvl_w[l];
        const int Hh = c_lvl_h[l];
        const uint32_t opk = *(const uint32_t*)(oa + (size_t)row * 384 + h * 32 + lp * 2);
        const float ox = bflo(opk), oy = bfhi(opk);
        const float rx = refp[((size_t)row * 4 + l) * 2 + 0];
        const float ry = refp[((size_t)row * 4 + l) * 2 + 1];
        const float x = (rx + ox / (float)Ww) * (float)Ww - 0.5f;
        const float y = (ry + oy / (float)Hh) * (float)Hh - 0.5f;
        const float xf = floorf(x), yf = floorf(y);
        const float fx = x - xf,    fy = y - yf;
        const int x0 = (int)xf, y0 = (int)yf;
        const int n  = (row >= LEN_IN) ? 1 : 0;
        const int lvlbase = n * LEN_IN + c_lvl_s[l];
        const float a = sw[t * 8 + h][lp];
        // x window: xs = clamp(x0, 0, W-2); loaded positions xs, xs+1
        const int xs = min(max(x0, 0), Ww - 2);
        const int d  = x0 - xs;   // -1: only right corner (at xs); 0: both; 1: only left (at xs+1)
        const float wxl = 1.f - fx, wxr = fx;
        const float pw0 = (d == 0) ? wxl : ((d == -1) ? wxr : 0.f);
        const float pw1 = (d == 0) ? wxr : ((d == 1) ? wxl : 0.f);
        uint32_t* p = sc + (t * 8 + h) * 132 + lp * 8;
        #pragma unroll
        for (int dy = 0; dy < 2; ++dy) {
            const int yi = y0 + dy;
            const int yc = min(max(yi, 0), Hh - 1);
            const bool yv = (yi >= 0) & (yi < Hh);
            const float wy = (dy ? fy : 1.f - fy) * (yv ? a : 0.f);
            const uint32_t boff = (uint32_t)(lvlbase + yc * Ww + xs) * 64u;  // BYTE offset in plane
            u32x4 pk = { boff, __float_as_uint(pw0 * wy), __float_as_uint(pw1 * wy), 0u };
            *(u32x4*)(p + dy * 4) = pk;
        }
    }
    __syncthreads();

    // ---- phase 3: gather. wave = 1 token; lane = (h, c8); c8<4 -> xs row, c8>=4 -> xs+1 row
    const int t  = tid >> 6;
    const int h  = (tid >> 3) & 7;
    const int c8 = tid & 7;
    const uint32_t* mb = sc + (t * 8 + h) * 132;
    const char* __restrict__ vpb = (const char*)(value + (size_t)h * (M_PAD * 32));
    const uint32_t lsub = (uint32_t)c8 * 16u;
    const bool hi = (c8 >= 4);
    float acc[8] = {};
    #pragma unroll 8
    for (int qd = 0; qd < 32; ++qd) {
        const u32x4 md = *(const u32x4*)(mb + qd * 4);
        const float w = __uint_as_float(hi ? md.z : md.y);
        const u32x4 v = *(const u32x4*)(vpb + (size_t)(md.x + lsub));
        #pragma unroll
        for (int d2 = 0; d2 < 4; ++d2) {
            acc[2 * d2]     += w * bflo(v[d2]);
            acc[2 * d2 + 1] += w * bfhi(v[d2]);
        }
    }
    #pragma unroll
    for (int j = 0; j < 8; ++j) acc[j] += __shfl_xor(acc[j], 4);
    if (c8 < 4) {
        bf16x8 o;
        #pragma unroll
        for (int j = 0; j < 8; ++j) o[j] = (__bf16)acc[j];
        const int orow = blk * 4 + t;
        *(bf16x8*)(out + (size_t)orow * 256 + h * 32 + c8 * 8) = o;
    }
}

// ---------------- launch ----------------
extern "C" void kernel_launch(void* const* d_in, const int* in_sizes, int n_in,
                              void* d_out, int out_size, void* d_ws, size_t ws_size,
                              hipStream_t stream)
{
    const float* src     = (const float*)d_in[0];
    const float* pos     = (const float*)d_in[1];
    const float* refp    = (const float*)d_in[2];
    const float* W_value = (const float*)d_in[5];
    const float* b_value = (const float*)d_in[6];
    const float* W_off   = (const float*)d_in[7];
    const float* b_off   = (const float*)d_in[8];
    const float* W_attn  = (const float*)d_in[9];
    const float* b_attn  = (const float*)d_in[10];
    const float* W_out   = (const float*)d_in[11];
    const float* b_out   = (const float*)d_in[12];
    const float* W1      = (const float*)d_in[13];
    const float* b1      = (const float*)d_in[14];
    const float* W2      = (const float*)d_in[15];
    const float* b2      = (const float*)d_in[16];
    const float* g1      = (const float*)d_in[17];
    const float* be1     = (const float*)d_in[18];
    const float* g2      = (const float*)d_in[19];
    const float* be2     = (const float*)d_in[20];
    float* outp = (float*)d_out;

    const int M = M_TOK;
    char* ws = (char*)d_ws;
    const size_t R2 = (size_t)M_PAD * 512;   // bytes of one [Mpad,256] bf16 buffer

    __bf16* src_b = (__bf16*)(ws);                    // [0, R2)
    __bf16* q_b   = (__bf16*)(ws + R2);               // [R2, 2R2)
    __bf16* val_b = (__bf16*)(ws + 2 * R2);           // [2R2, 3R2)  head-major [8][Mpad][32]
    __bf16* oa    = (__bf16*)(ws + 3 * R2);           // [3R2, 4.5R2)
    __bf16* samp  = (__bf16*)(ws + 9 * R2 / 2);       // [4.5R2, 5.5R2)
    __bf16* x_b   = (__bf16*)(ws + 11 * R2 / 2);      // [5.5R2, 6.5R2)
    __bf16* hbuf  = (__bf16*)(ws);                    // [0, 4R2) overlay (dead by FFN1)
    __bf16* wbase = (__bf16*)(ws + 13 * R2 / 2);
    __bf16* Wt_value = wbase;                          // [256][256]
    __bf16* Wt_oa    = wbase + 65536;                  // [384][256]
    __bf16* Wt_out   = wbase + 163840;                 // [256][256]
    __bf16* Wt1      = wbase + 229376;                 // [1024][256]
    __bf16* Wt2      = wbase + 491520;                 // [256][1024]
    float*  bias_oa  = (float*)(wbase + 753664);       // [384]

    const dim3 blk(256);
    const int n4 = M * 256 / 4;
    const int gm = M_PAD / 128;  // 208

    prep<<<dim3(737 + (n4 + 255) / 256), blk, 0, stream>>>(
        W_value, W_off, W_attn, W_out, W1, W2,
        Wt_value, Wt_oa, Wt_oa + 65536, Wt_out, Wt1, Wt2,
        b_off, b_attn, bias_oa,
        (const float4*)src, (const float4*)pos, (bf16x4*)src_b, (bf16x4*)q_b, n4);

    // value (2 n-tiles, head-major) + oa (3 n-tiles): 5 x 208 = 1040 blocks
    gemm_front<<<dim3(5, gm), blk, 0, stream>>>(
        src_b, Wt_value, b_value, val_b,
        q_b,   Wt_oa,    bias_oa, oa, M);

    msda_sample<<<dim3(M / 4), blk, 0, stream>>>(val_b, oa, refp, samp);

    // x_b = LN(src + samp @ W_out + b_out)  (bf16), 32-row blocks, BK=32
    gemm_ln<__bf16, 256><<<dim3(M_PAD / 32), blk, 0, stream>>>(
        samp, Wt_out, b_out, src_b, g1, be1, x_b, M);

    // hbuf = relu(x_b @ W1 + b1)
    gemm_ffn1<<<dim3(8, gm), blk, 0, stream>>>(x_b, Wt1, b1, hbuf, M);

    // out = LN(x_b + hbuf @ W2 + b2)  (fp32, to d_out), 32-row blocks, BK=32
    gemm_ln<float, 1024><<<dim3(M_PAD / 32), blk, 0, stream>>>(
        hbuf, Wt2, b2, x_b, g2, be2, outp, M);
}

// Round 5
// 299.702 us; speedup vs baseline: 1.0360x; 1.0068x over previous
//
#include <hip/hip_runtime.h>
#include <hip/hip_bf16.h>
#include <cstdint>

// ---------------- static problem config ----------------
#define D_MODEL   256
#define N_HEADS   8
#define N_LEVELS  4
#define N_POINTS  4
#define D_FFN     1024
#define D_HEAD    32
#define LEN_IN    13294          // 100*100 + 50*50 + 25*25 + 13*13
#define NBATCH    2
#define M_TOK     (NBATCH * LEN_IN)   // 26588
#define M_PAD     26624               // 208*128 = 416*64 = 832*32

__constant__ int c_lvl_h[4] = {100, 50, 25, 13};
__constant__ int c_lvl_w[4] = {100, 50, 25, 13};
__constant__ int c_lvl_s[4] = {0, 10000, 12500, 13125};

typedef __attribute__((ext_vector_type(8))) __bf16 bf16x8;
typedef __attribute__((ext_vector_type(4))) __bf16 bf16x4;
typedef __attribute__((ext_vector_type(4))) float  f32x4;
typedef __attribute__((ext_vector_type(4))) uint32_t u32x4;

__device__ __forceinline__ float bflo(uint32_t w) { return __uint_as_float(w << 16); }
__device__ __forceinline__ float bfhi(uint32_t w) { return __uint_as_float(w & 0xffff0000u); }

// async global->LDS, 16B per lane; lds base wave-uniform (lane i lands at base + i*16)
__device__ __forceinline__ void lds_direct16(const void* g, void* l) {
    __builtin_amdgcn_global_load_lds(
        (const __attribute__((address_space(1))) uint32_t*)(uintptr_t)g,
        (__attribute__((address_space(3))) uint32_t*)(uintptr_t)l,
        16, 0, 0);
}

// ---------------- prep: weight transposes + bias concat + src/q cvt, ONE dispatch ----------------
__global__ __launch_bounds__(256) void prep(
    const float* __restrict__ s0, const float* __restrict__ s1, const float* __restrict__ s2,
    const float* __restrict__ s3, const float* __restrict__ s4, const float* __restrict__ s5,
    __bf16* __restrict__ d0, __bf16* __restrict__ d1, __bf16* __restrict__ d2,
    __bf16* __restrict__ d3, __bf16* __restrict__ d4, __bf16* __restrict__ d5,
    const float* __restrict__ b_off, const float* __restrict__ b_attn,
    float* __restrict__ bias_oa,
    const float4* __restrict__ src, const float4* __restrict__ pos,
    bf16x4* __restrict__ sb, bf16x4* __restrict__ qb, int n4)
{
    const int tid = threadIdx.x;
    const int b = blockIdx.x;
    if (b >= 737) {   // cvt path
        const int i = (b - 737) * 256 + tid;
        if (i >= n4) return;
        const float4 s = src[i];
        const float4 p = pos[i];
        bf16x4 sv = { (__bf16)s.x, (__bf16)s.y, (__bf16)s.z, (__bf16)s.w };
        bf16x4 qv = { (__bf16)(s.x + p.x), (__bf16)(s.y + p.y),
                      (__bf16)(s.z + p.z), (__bf16)(s.w + p.w) };
        sb[i] = sv;
        qb[i] = qv;
        return;
    }
    if (b == 736) {   // bias concat: [b_off(256) | b_attn(128)]
        if (tid < 256) bias_oa[tid] = b_off[tid];
        if (tid < 128) bias_oa[256 + tid] = b_attn[tid];
        return;
    }
    const int tx = tid & 31;
    const int ty = tid >> 5;
    const int starts[7] = {0, 64, 128, 160, 224, 480, 736};
    const int Ks[6] = {256, 256, 256, 256, 256, 1024};
    const int Ns[6] = {256, 256, 128, 256, 1024, 256};
    const float* srcs[6] = {s0, s1, s2, s3, s4, s5};
    __bf16* dsts[6] = {d0, d1, d2, d3, d4, d5};
    int i = 0;
    while (b >= starts[i + 1]) ++i;
    const int t = b - starts[i];
    const int K = Ks[i], N = Ns[i];
    const float* W = srcs[i];
    __bf16* Wt = dsts[i];
    const int ntx = N >> 5;
    const int n0 = (t % ntx) * 32;
    const int k0 = (t / ntx) * 32;

    __shared__ float tl[32][33];
    #pragma unroll
    for (int j = 0; j < 4; ++j)
        tl[ty + j * 8][tx] = W[(size_t)(k0 + ty + j * 8) * N + n0 + tx];
    __syncthreads();
    #pragma unroll
    for (int j = 0; j < 4; ++j)
        Wt[(size_t)(n0 + ty + j * 8) * K + k0 + tx] = (__bf16)tl[tx][ty + j * 8];
}

// ---------------- bf16 MFMA GEMM core (m97 structure, 128x128 tile, NP=2) ----------------
// C[M,N] = act(A @ Bt^T + bias), bf16 output. Coalesced LDS-assembled epilogue.
// HEADMAJOR: C is [col/32][Mpad][32] planes; stores remapped plane-major so each
// wave writes 1KB contiguous inside one plane (rows adjacent at 64B stride).
template <bool RELU, int K, bool HEADMAJOR>
__device__ __forceinline__ void gemm_core(
    const __bf16* __restrict__ A, const __bf16* __restrict__ Bt,
    const float* __restrict__ bias, __bf16* __restrict__ C,
    int M, int N, int bm, int bn)
{
    // staging: As 2*128*32 (8K elems) + Bs 2*128*32 (8K elems) = 16K elems
    // epilogue: C-tile 128 x 136 = 17408 elems (overlays both)
    __shared__ __bf16 smem[17408];
    __bf16* As = smem;
    __bf16* Bs = smem + 8192;

    const int tid  = threadIdx.x;
    const int lane = tid & 63;
    const int wv   = tid >> 6;
    const int wm   = (wv >> 1) * 64;
    const int wn   = (wv & 1) * 64;
    const int srow = lane >> 2;
    const int skc  = (lane & 3) * 8;
    const int fm   = lane & 15;
    const int fko  = (lane >> 4) * 8;

    f32x4 acc[4][4] = {};

    for (int k0 = 0; k0 < K; k0 += 64) {
        #pragma unroll
        for (int p = 0; p < 2; ++p) {
            #pragma unroll
            for (int c = 0; c < 2; ++c) {
                const int r = wv * 32 + c * 16;
                lds_direct16(A  + (size_t)(bm + r + srow) * K + k0 + p * 32 + skc, As + p * 4096 + r * 32);
                lds_direct16(Bt + (size_t)(bn + r + srow) * K + k0 + p * 32 + skc, Bs + p * 4096 + r * 32);
            }
        }
        __syncthreads();

        #pragma unroll
        for (int p = 0; p < 2; ++p) {
            bf16x8 af[4], bfr[4];
            #pragma unroll
            for (int t = 0; t < 4; ++t) {
                af[t]  = *(const bf16x8*)(As + p * 4096 + (wm + t * 16 + fm) * 32 + fko);
                bfr[t] = *(const bf16x8*)(Bs + p * 4096 + (wn + t * 16 + fm) * 32 + fko);
            }
            #pragma unroll
            for (int mt = 0; mt < 4; ++mt)
                #pragma unroll
                for (int nt = 0; nt < 4; ++nt)
                    acc[mt][nt] = __builtin_amdgcn_mfma_f32_16x16x32_bf16(
                        af[mt], bfr[nt], acc[mt][nt], 0, 0, 0);
        }
        __syncthreads();
    }

    // epilogue: C/D layout col=lane&15, row=(lane>>4)*4+reg [m89-verified]
    // assemble bf16 tile in LDS (stride 136), then coalesced bf16x8 stores.
    const int ecol = lane & 15;
    const int erow = (lane >> 4) * 4;
    #pragma unroll
    for (int nt = 0; nt < 4; ++nt) {
        const int cl = wn + nt * 16 + ecol;
        const float bv = bias[bn + cl];
        #pragma unroll
        for (int mt = 0; mt < 4; ++mt) {
            #pragma unroll
            for (int r = 0; r < 4; ++r) {
                const int rl = wm + mt * 16 + erow + r;
                float v = acc[mt][nt][r] + bv;
                if (RELU) v = fmaxf(v, 0.f);
                smem[rl * 136 + cl] = (__bf16)v;
            }
        }
    }
    __syncthreads();
    #pragma unroll
    for (int rr = 0; rr < 8; ++rr) {
        const int idx = rr * 256 + tid;
        if (HEADMAJOR) {
            const int plane = idx >> 9;          // 4 planes of 32 cols in this 128-col tile
            const int row   = (idx >> 2) & 127;
            const int ch4   = idx & 3;
            if (bm + row < M)
                *(bf16x8*)(C + ((size_t)((bn >> 5) + plane) * M_PAD + (bm + row)) * 32 + ch4 * 8) =
                    *(const bf16x8*)(smem + row * 136 + plane * 32 + ch4 * 8);
        } else {
            const int row = idx >> 4;
            const int ch  = idx & 15;
            if (bm + row < M)
                *(bf16x8*)(C + (size_t)(bm + row) * N + bn + ch * 8) =
                    *(const bf16x8*)(smem + row * 136 + ch * 8);
        }
    }
}

// front GEMM: blocks x<2 -> value (src_b @ Wt_value, head-major), x>=2 -> oa (q_b @ Wt_oa)
__global__ __launch_bounds__(256) void gemm_front(
    const __bf16* __restrict__ A0, const __bf16* __restrict__ B0,
    const float* __restrict__ bi0, __bf16* __restrict__ C0,
    const __bf16* __restrict__ A1, const __bf16* __restrict__ B1,
    const float* __restrict__ bi1, __bf16* __restrict__ C1, int M)
{
    const int bx = blockIdx.x;
    if (bx < 2)
        gemm_core<false, 256, true>(A0, B0, bi0, C0, M, 256, blockIdx.y * 128, bx * 128);
    else
        gemm_core<false, 256, false>(A1, B1, bi1, C1, M, 384, blockIdx.y * 128, (bx - 2) * 128);
}

// FFN1: relu(x_b @ W1 + b1), N=1024
__global__ __launch_bounds__(256) void gemm_ffn1(
    const __bf16* __restrict__ A, const __bf16* __restrict__ Bt,
    const float* __restrict__ bias, __bf16* __restrict__ C, int M)
{
    gemm_core<true, 256, false>(A, Bt, bias, C, M, 1024, blockIdx.y * 128, blockIdx.x * 128);
}

// ---------------- GEMM + residual + LayerNorm fused (32x256 tile, BK=32, 4 waves) ----------------
// 2-phase double-buffered pipeline (T3-minimum): stage tile t+1 BEFORE computing
// tile t; one vmcnt(0)+barrier per tile (the barrier's implicit drain). Load
// latency for t+1 hides under compute(t). LDS 36.8KB -> 4 blocks/CU.
template <typename OutT, int K>
__global__ __launch_bounds__(256, 4) void gemm_ln(
    const __bf16* __restrict__ A, const __bf16* __restrict__ Bt,
    const float* __restrict__ bias, const __bf16* __restrict__ res,
    const float* __restrict__ gamma, const float* __restrict__ beta,
    OutT* __restrict__ Cout, int M)
{
    // staging per buffer: As 32*32 (2KB) + Bs 256*32 (16KB) = 9216 elems (18KB); x2 buffers
    // epilogue overlay: bf16 tile 32x264 = 16.9KB; fp32 half-tile 16x260 = 16.6KB (fits buf0)
    __shared__ __bf16 smem[2][9216];
    __shared__ float lnsum[32][4];
    __shared__ float lnsq[32][4];
    __shared__ float lnstat[32][2];

    const int tid  = threadIdx.x;
    const int lane = tid & 63;
    const int wv   = tid >> 6;
    const int bm   = blockIdx.x * 32;
    const int wn   = wv * 64;
    const int srow = lane >> 2;
    const int skc  = (lane & 3) * 8;
    const int fm   = lane & 15;
    const int fko  = (lane >> 4) * 8;

    f32x4 acc[2][4] = {};

    // stage tile into buffer b at K-offset k0
    auto stage = [&](int b, int k0) {
        __bf16* As = smem[b];
        __bf16* Bs = smem[b] + 1024;
        if (tid < 128)
            lds_direct16(A + (size_t)(bm + (tid >> 2)) * K + k0 + (tid & 3) * 8,
                         As + tid * 8);
        #pragma unroll
        for (int c = 0; c < 4; ++c) {
            const int r = wv * 64 + c * 16;
            lds_direct16(Bt + (size_t)(r + srow) * K + k0 + skc, Bs + r * 32);
        }
    };
    // compute one BK=32 tile from buffer b
    auto compute = [&](int b) {
        const __bf16* As = smem[b];
        const __bf16* Bs = smem[b] + 1024;
        bf16x8 af[2], bfr[4];
        #pragma unroll
        for (int mt = 0; mt < 2; ++mt)
            af[mt] = *(const bf16x8*)(As + (mt * 16 + fm) * 32 + fko);
        #pragma unroll
        for (int nt = 0; nt < 4; ++nt)
            bfr[nt] = *(const bf16x8*)(Bs + (wn + nt * 16 + fm) * 32 + fko);
        #pragma unroll
        for (int mt = 0; mt < 2; ++mt)
            #pragma unroll
            for (int nt = 0; nt < 4; ++nt)
                acc[mt][nt] = __builtin_amdgcn_mfma_f32_16x16x32_bf16(
                    af[mt], bfr[nt], acc[mt][nt], 0, 0, 0);
    };

    stage(0, 0);
    __syncthreads();            // drains vmcnt(0): buf0 ready
    int cur = 0;
    for (int k0 = 32; k0 < K; k0 += 32) {
        stage(cur ^ 1, k0);     // issue next tile's loads FIRST (latency hides under compute)
        compute(cur);
        __syncthreads();        // vmcnt(0)+lgkm drain: next buffer ready, cur reads done
        cur ^= 1;
    }
    compute(cur);               // last tile (no further staging)

    const int ecol = lane & 15;
    const int erow = (lane >> 4) * 4;

    // bias + residual
    float g4[4], b4[4];
    #pragma unroll
    for (int nt = 0; nt < 4; ++nt) {
        const int col = wn + nt * 16 + ecol;
        g4[nt] = gamma[col];
        b4[nt] = beta[col];
        const float bv = bias[col];
        #pragma unroll
        for (int mt = 0; mt < 2; ++mt) {
            #pragma unroll
            for (int r = 0; r < 4; ++r) {
                const int row = bm + mt * 16 + erow + r;
                acc[mt][nt][r] += bv + (float)res[(size_t)row * 256 + col];
            }
        }
    }

    // per-row sums (wave's 64-col slice), 16-lane shuffle reduce
    #pragma unroll
    for (int mt = 0; mt < 2; ++mt) {
        #pragma unroll
        for (int r = 0; r < 4; ++r) {
            float s  = acc[mt][0][r] + acc[mt][1][r] + acc[mt][2][r] + acc[mt][3][r];
            float s2 = acc[mt][0][r] * acc[mt][0][r] + acc[mt][1][r] * acc[mt][1][r]
                     + acc[mt][2][r] * acc[mt][2][r] + acc[mt][3][r] * acc[mt][3][r];
            #pragma unroll
            for (int o = 1; o < 16; o <<= 1) {
                s  += __shfl_xor(s, o);
                s2 += __shfl_xor(s2, o);
            }
            if (ecol == 0) {
                const int rl = mt * 16 + erow + r;
                lnsum[rl][wv] = s;
                lnsq[rl][wv]  = s2;
            }
        }
    }
    __syncthreads();
    if (tid < 32) {
        const float s  = lnsum[tid][0] + lnsum[tid][1] + lnsum[tid][2] + lnsum[tid][3];
        const float s2 = lnsq[tid][0] + lnsq[tid][1] + lnsq[tid][2] + lnsq[tid][3];
        const float mu = s * (1.f / 256.f);
        const float var = s2 * (1.f / 256.f) - mu * mu;
        lnstat[tid][0] = mu;
        lnstat[tid][1] = rsqrtf(var + 1e-5f);
    }
    __syncthreads();

    // normalize into LDS tile, then coalesced stores
    if constexpr (sizeof(OutT) == 2) {
        __bf16* ct = smem[0];   // [32][264]
        #pragma unroll
        for (int mt = 0; mt < 2; ++mt) {
            #pragma unroll
            for (int r = 0; r < 4; ++r) {
                const int rl = mt * 16 + erow + r;
                const float mu = lnstat[rl][0];
                const float rs = lnstat[rl][1];
                #pragma unroll
                for (int nt = 0; nt < 4; ++nt) {
                    const int col = wn + nt * 16 + ecol;
                    ct[rl * 264 + col] = (__bf16)((acc[mt][nt][r] - mu) * rs * g4[nt] + b4[nt]);
                }
            }
        }
        __syncthreads();
        #pragma unroll
        for (int rr = 0; rr < 4; ++rr) {
            const int idx = rr * 256 + tid;
            const int row = idx >> 5;
            const int ch  = idx & 31;
            if (bm + row < M)
                *(bf16x8*)((__bf16*)Cout + (size_t)(bm + row) * 256 + ch * 8) =
                    *(const bf16x8*)(ct + row * 264 + ch * 8);
        }
    } else {
        float* ct = (float*)smem[0];   // [16][260] per half
        #pragma unroll
        for (int hf = 0; hf < 2; ++hf) {
            const int mt = hf;
            #pragma unroll
            for (int r = 0; r < 4; ++r) {
                const int rl   = mt * 16 + erow + r;
                const int rloc = erow + r;
                const float mu = lnstat[rl][0];
                const float rs = lnstat[rl][1];
                #pragma unroll
                for (int nt = 0; nt < 4; ++nt) {
                    const int col = wn + nt * 16 + ecol;
                    ct[rloc * 260 + col] = (acc[mt][nt][r] - mu) * rs * g4[nt] + b4[nt];
                }
            }
            __syncthreads();
            #pragma unroll
            for (int rr = 0; rr < 4; ++rr) {
                const int idx = rr * 256 + tid;
                const int row = idx >> 6;
                const int ch  = idx & 63;
                const int grow = bm + hf * 16 + row;
                if (grow < M) {
                    float4 v = *(const float4*)(ct + row * 260 + ch * 4);
                    *(float4*)((float*)Cout + (size_t)grow * 256 + ch * 4) = v;
                }
            }
            __syncthreads();
        }
    }
}

// ---------------- deformable sampling ----------------
// value is HEAD-MAJOR: [8][Mpad][32] bf16, so corner x-pairs are 128B contiguous.
// 4 tokens per block, 256 thr = 4 tok x 8 heads x 8 lanes; per (q,dy) each lane
// loads dwordx4 of a 128B window covering BOTH x-corners (lanes 0-3: xs row,
// 4-7: xs+1 row). shfl_xor(4) folds the halves at the end.
__global__ __launch_bounds__(256) void msda_sample(
    const __bf16* __restrict__ value, // [8][Mpad][32] bf16, head-major planes
    const __bf16* __restrict__ oa,    // [Mpad, 384] bf16: [off(256) | attn(128)]
    const float* __restrict__ refp,   // [M, 4, 2]
    __bf16* __restrict__ out)         // [Mpad, 256] bf16
{
    __shared__ uint32_t sc[32 * 132]; // per (t,h): 16q x 2dy x {boff,w0,w1,pad} ; 16.9 KB
    __shared__ float sw[32][16];      // softmax weights ; 2 KB

    const int tid = threadIdx.x;
    const int blk = blockIdx.x;

    // ---- phase 1: softmax, one (token,head) per thread (32 threads)
    if (tid < 32) {
        const int t = tid >> 3;
        const int h = tid & 7;
        const int row = blk * 4 + t;
        const __bf16* ap = oa + (size_t)row * 384 + 256 + h * 16;
        const bf16x8 v0 = *(const bf16x8*)ap;
        const bf16x8 v1 = *(const bf16x8*)(ap + 8);
        float e[16];
        #pragma unroll
        for (int i = 0; i < 8; ++i) { e[i] = (float)v0[i]; e[8 + i] = (float)v1[i]; }
        float mx = -1e30f;
        #pragma unroll
        for (int i = 0; i < 16; ++i) mx = fmaxf(mx, e[i]);
        float s = 0.f;
        #pragma unroll
        for (int i = 0; i < 16; ++i) { e[i] = __expf(e[i] - mx); s += e[i]; }
        const float inv = 1.f / s;
        #pragma unroll
        for (int i = 0; i < 16; ++i) sw[tid][i] = e[i] * inv;
    }
    __syncthreads();

    // ---- phase 2: per (t,h,lp): two x-pair entries (dy=0,1), 2 items per thread
    #pragma unroll
    for (int it = 0; it < 2; ++it) {
        const int idx = it * 256 + tid;       // 0..511 = t*128 + h*16 + lp
        const int t  = idx >> 7;
        const int h  = (idx >> 4) & 7;
        const int lp = idx & 15;
        const int l  = lp >> 2;
        const int row = blk * 4 + t;
        const int Ww = c_lvl_w[l];
        const int Hh = c_lvl_h[l];
        const uint32_t opk = *(const uint32_t*)(oa + (size_t)row * 384 + h * 32 + lp * 2);
        const float ox = bflo(opk), oy = bfhi(opk);
        const float rx = refp[((size_t)row * 4 + l) * 2 + 0];
        const float ry = refp[((size_t)row * 4 + l) * 2 + 1];
        const float x = (rx + ox / (float)Ww) * (float)Ww - 0.5f;
        const float y = (ry + oy / (float)Hh) * (float)Hh - 0.5f;
        const float xf = floorf(x), yf = floorf(y);
        const float fx = x - xf,    fy = y - yf;
        const int x0 = (int)xf, y0 = (int)yf;
        const int n  = (row >= LEN_IN) ? 1 : 0;
        const int lvlbase = n * LEN_IN + c_lvl_s[l];
        const float a = sw[t * 8 + h][lp];
        // x window: xs = clamp(x0, 0, W-2); loaded positions xs, xs+1
        const int xs = min(max(x0, 0), Ww - 2);
        const int d  = x0 - xs;   // -1: only right corner (at xs); 0: both; 1: only left (at xs+1)
        const float wxl = 1.f - fx, wxr = fx;
        const float pw0 = (d == 0) ? wxl : ((d == -1) ? wxr : 0.f);
        const float pw1 = (d == 0) ? wxr : ((d == 1) ? wxl : 0.f);
        uint32_t* p = sc + (t * 8 + h) * 132 + lp * 8;
        #pragma unroll
        for (int dy = 0; dy < 2; ++dy) {
            const int yi = y0 + dy;
            const int yc = min(max(yi, 0), Hh - 1);
            const bool yv = (yi >= 0) & (yi < Hh);
            const float wy = (dy ? fy : 1.f - fy) * (yv ? a : 0.f);
            const uint32_t boff = (uint32_t)(lvlbase + yc * Ww + xs) * 64u;  // BYTE offset in plane
            u32x4 pk = { boff, __float_as_uint(pw0 * wy), __float_as_uint(pw1 * wy), 0u };
            *(u32x4*)(p + dy * 4) = pk;
        }
    }
    __syncthreads();

    // ---- phase 3: gather. wave = 1 token; lane = (h, c8); c8<4 -> xs row, c8>=4 -> xs+1 row
    const int t  = tid >> 6;
    const int h  = (tid >> 3) & 7;
    const int c8 = tid & 7;
    const uint32_t* mb = sc + (t * 8 + h) * 132;
    const char* __restrict__ vpb = (const char*)(value + (size_t)h * (M_PAD * 32));
    const uint32_t lsub = (uint32_t)c8 * 16u;
    const bool hi = (c8 >= 4);
    float acc[8] = {};
    #pragma unroll 8
    for (int qd = 0; qd < 32; ++qd) {
        const u32x4 md = *(const u32x4*)(mb + qd * 4);
        const float w = __uint_as_float(hi ? md.z : md.y);
        const u32x4 v = *(const u32x4*)(vpb + (size_t)(md.x + lsub));
        #pragma unroll
        for (int d2 = 0; d2 < 4; ++d2) {
            acc[2 * d2]     += w * bflo(v[d2]);
            acc[2 * d2 + 1] += w * bfhi(v[d2]);
        }
    }
    #pragma unroll
    for (int j = 0; j < 8; ++j) acc[j] += __shfl_xor(acc[j], 4);
    if (c8 < 4) {
        bf16x8 o;
        #pragma unroll
        for (int j = 0; j < 8; ++j) o[j] = (__bf16)acc[j];
        const int orow = blk * 4 + t;
        *(bf16x8*)(out + (size_t)orow * 256 + h * 32 + c8 * 8) = o;
    }
}

// ---------------- launch ----------------
extern "C" void kernel_launch(void* const* d_in, const int* in_sizes, int n_in,
                              void* d_out, int out_size, void* d_ws, size_t ws_size,
                              hipStream_t stream)
{
    const float* src     = (const float*)d_in[0];
    const float* pos     = (const float*)d_in[1];
    const float* refp    = (const float*)d_in[2];
    const float* W_value = (const float*)d_in[5];
    const float* b_value = (const float*)d_in[6];
    const float* W_off   = (const float*)d_in[7];
    const float* b_off   = (const float*)d_in[8];
    const float* W_attn  = (const float*)d_in[9];
    const float* b_attn  = (const float*)d_in[10];
    const float* W_out   = (const float*)d_in[11];
    const float* b_out   = (const float*)d_in[12];
    const float* W1      = (const float*)d_in[13];
    const float* b1      = (const float*)d_in[14];
    const float* W2      = (const float*)d_in[15];
    const float* b2      = (const float*)d_in[16];
    const float* g1      = (const float*)d_in[17];
    const float* be1     = (const float*)d_in[18];
    const float* g2      = (const float*)d_in[19];
    const float* be2     = (const float*)d_in[20];
    float* outp = (float*)d_out;

    const int M = M_TOK;
    char* ws = (char*)d_ws;
    const size_t R2 = (size_t)M_PAD * 512;   // bytes of one [Mpad,256] bf16 buffer

    __bf16* src_b = (__bf16*)(ws);                    // [0, R2)
    __bf16* q_b   = (__bf16*)(ws + R2);               // [R2, 2R2)
    __bf16* val_b = (__bf16*)(ws + 2 * R2);           // [2R2, 3R2)  head-major [8][Mpad][32]
    __bf16* oa    = (__bf16*)(ws + 3 * R2);           // [3R2, 4.5R2)
    __bf16* samp  = (__bf16*)(ws + 9 * R2 / 2);       // [4.5R2, 5.5R2)
    __bf16* x_b   = (__bf16*)(ws + 11 * R2 / 2);      // [5.5R2, 6.5R2)
    __bf16* hbuf  = (__bf16*)(ws);                    // [0, 4R2) overlay (dead by FFN1)
    __bf16* wbase = (__bf16*)(ws + 13 * R2 / 2);
    __bf16* Wt_value = wbase;                          // [256][256]
    __bf16* Wt_oa    = wbase + 65536;                  // [384][256]
    __bf16* Wt_out   = wbase + 163840;                 // [256][256]
    __bf16* Wt1      = wbase + 229376;                 // [1024][256]
    __bf16* Wt2      = wbase + 491520;                 // [256][1024]
    float*  bias_oa  = (float*)(wbase + 753664);       // [384]

    const dim3 blk(256);
    const int n4 = M * 256 / 4;
    const int gm = M_PAD / 128;  // 208

    prep<<<dim3(737 + (n4 + 255) / 256), blk, 0, stream>>>(
        W_value, W_off, W_attn, W_out, W1, W2,
        Wt_value, Wt_oa, Wt_oa + 65536, Wt_out, Wt1, Wt2,
        b_off, b_attn, bias_oa,
        (const float4*)src, (const float4*)pos, (bf16x4*)src_b, (bf16x4*)q_b, n4);

    // value (2 n-tiles, head-major) + oa (3 n-tiles): 5 x 208 = 1040 blocks
    gemm_front<<<dim3(5, gm), blk, 0, stream>>>(
        src_b, Wt_value, b_value, val_b,
        q_b,   Wt_oa,    bias_oa, oa, M);

    msda_sample<<<dim3(M / 4), blk, 0, stream>>>(val_b, oa, refp, samp);

    // x_b = LN(src + samp @ W_out + b_out)  (bf16), 32-row blocks, BK=32, 2-phase
    gemm_ln<__bf16, 256><<<dim3(M_PAD / 32), blk, 0, stream>>>(
        samp, Wt_out, b_out, src_b, g1, be1, x_b, M);

    // hbuf = relu(x_b @ W1 + b1)
    gemm_ffn1<<<dim3(8, gm), blk, 0, stream>>>(x_b, Wt1, b1, hbuf, M);

    // out = LN(x_b + hbuf @ W2 + b2)  (fp32, to d_out), 32-row blocks, BK=32, 2-phase
    gemm_ln<float, 1024><<<dim3(M_PAD / 32), blk, 0, stream>>>(
        hbuf, Wt2, b2, x_b, g2, be2, outp, M);
}

// Round 6
// 298.162 us; speedup vs baseline: 1.0413x; 1.0052x over previous
//
#include <hip/hip_runtime.h>
#include <hip/hip_bf16.h>
#include <cstdint>

// ---------------- static problem config ----------------
#define D_MODEL   256
#define N_HEADS   8
#define N_LEVELS  4
#define N_POINTS  4
#define D_FFN     1024
#define D_HEAD    32
#define LEN_IN    13294          // 100*100 + 50*50 + 25*25 + 13*13
#define NBATCH    2
#define M_TOK     (NBATCH * LEN_IN)   // 26588
#define M_PAD     26624               // 208*128 = 416*64 = 832*32

__constant__ int c_lvl_h[4] = {100, 50, 25, 13};
__constant__ int c_lvl_w[4] = {100, 50, 25, 13};
__constant__ int c_lvl_s[4] = {0, 10000, 12500, 13125};

typedef __attribute__((ext_vector_type(8))) __bf16 bf16x8;
typedef __attribute__((ext_vector_type(4))) __bf16 bf16x4;
typedef __attribute__((ext_vector_type(4))) float  f32x4;
typedef __attribute__((ext_vector_type(4))) uint32_t u32x4;

__device__ __forceinline__ float bflo(uint32_t w) { return __uint_as_float(w << 16); }
__device__ __forceinline__ float bfhi(uint32_t w) { return __uint_as_float(w & 0xffff0000u); }

// async global->LDS, 16B per lane; lds base wave-uniform (lane i lands at base + i*16)
__device__ __forceinline__ void lds_direct16(const void* g, void* l) {
    __builtin_amdgcn_global_load_lds(
        (const __attribute__((address_space(1))) uint32_t*)(uintptr_t)g,
        (__attribute__((address_space(3))) uint32_t*)(uintptr_t)l,
        16, 0, 0);
}

// ---------------- prep: weight transposes + bias concat + src/q cvt, ONE dispatch ----------------
__global__ __launch_bounds__(256) void prep(
    const float* __restrict__ s0, const float* __restrict__ s1, const float* __restrict__ s2,
    const float* __restrict__ s3, const float* __restrict__ s4, const float* __restrict__ s5,
    __bf16* __restrict__ d0, __bf16* __restrict__ d1, __bf16* __restrict__ d2,
    __bf16* __restrict__ d3, __bf16* __restrict__ d4, __bf16* __restrict__ d5,
    const float* __restrict__ b_off, const float* __restrict__ b_attn,
    float* __restrict__ bias_oa,
    const float4* __restrict__ src, const float4* __restrict__ pos,
    bf16x4* __restrict__ sb, bf16x4* __restrict__ qb, int n4)
{
    const int tid = threadIdx.x;
    const int b = blockIdx.x;
    if (b >= 737) {   // cvt path
        const int i = (b - 737) * 256 + tid;
        if (i >= n4) return;
        const float4 s = src[i];
        const float4 p = pos[i];
        bf16x4 sv = { (__bf16)s.x, (__bf16)s.y, (__bf16)s.z, (__bf16)s.w };
        bf16x4 qv = { (__bf16)(s.x + p.x), (__bf16)(s.y + p.y),
                      (__bf16)(s.z + p.z), (__bf16)(s.w + p.w) };
        sb[i] = sv;
        qb[i] = qv;
        return;
    }
    if (b == 736) {   // bias concat: [b_off(256) | b_attn(128)]
        if (tid < 256) bias_oa[tid] = b_off[tid];
        if (tid < 128) bias_oa[256 + tid] = b_attn[tid];
        return;
    }
    const int tx = tid & 31;
    const int ty = tid >> 5;
    const int starts[7] = {0, 64, 128, 160, 224, 480, 736};
    const int Ks[6] = {256, 256, 256, 256, 256, 1024};
    const int Ns[6] = {256, 256, 128, 256, 1024, 256};
    const float* srcs[6] = {s0, s1, s2, s3, s4, s5};
    __bf16* dsts[6] = {d0, d1, d2, d3, d4, d5};
    int i = 0;
    while (b >= starts[i + 1]) ++i;
    const int t = b - starts[i];
    const int K = Ks[i], N = Ns[i];
    const float* W = srcs[i];
    __bf16* Wt = dsts[i];
    const int ntx = N >> 5;
    const int n0 = (t % ntx) * 32;
    const int k0 = (t / ntx) * 32;

    __shared__ float tl[32][33];
    #pragma unroll
    for (int j = 0; j < 4; ++j)
        tl[ty + j * 8][tx] = W[(size_t)(k0 + ty + j * 8) * N + n0 + tx];
    __syncthreads();
    #pragma unroll
    for (int j = 0; j < 4; ++j)
        Wt[(size_t)(n0 + ty + j * 8) * K + k0 + tx] = (__bf16)tl[tx][ty + j * 8];
}

// ---------------- bf16 MFMA GEMM core (m97 structure, 128x128 tile, NP=2) ----------------
// C[M,N] = act(A @ Bt^T + bias), bf16 output. Coalesced LDS-assembled epilogue.
// HEADMAJOR: C is [col/32][Mpad][32] planes; stores remapped plane-major so each
// wave writes 1KB contiguous inside one plane (rows adjacent at 64B stride).
template <bool RELU, int K, bool HEADMAJOR>
__device__ __forceinline__ void gemm_core(
    const __bf16* __restrict__ A, const __bf16* __restrict__ Bt,
    const float* __restrict__ bias, __bf16* __restrict__ C,
    int M, int N, int bm, int bn)
{
    // staging: As 2*128*32 (8K elems) + Bs 2*128*32 (8K elems) = 16K elems
    // epilogue: C-tile 128 x 136 = 17408 elems (overlays both)
    __shared__ __bf16 smem[17408];
    __bf16* As = smem;
    __bf16* Bs = smem + 8192;

    const int tid  = threadIdx.x;
    const int lane = tid & 63;
    const int wv   = tid >> 6;
    const int wm   = (wv >> 1) * 64;
    const int wn   = (wv & 1) * 64;
    const int srow = lane >> 2;
    const int skc  = (lane & 3) * 8;
    const int fm   = lane & 15;
    const int fko  = (lane >> 4) * 8;

    f32x4 acc[4][4] = {};

    for (int k0 = 0; k0 < K; k0 += 64) {
        #pragma unroll
        for (int p = 0; p < 2; ++p) {
            #pragma unroll
            for (int c = 0; c < 2; ++c) {
                const int r = wv * 32 + c * 16;
                lds_direct16(A  + (size_t)(bm + r + srow) * K + k0 + p * 32 + skc, As + p * 4096 + r * 32);
                lds_direct16(Bt + (size_t)(bn + r + srow) * K + k0 + p * 32 + skc, Bs + p * 4096 + r * 32);
            }
        }
        __syncthreads();

        #pragma unroll
        for (int p = 0; p < 2; ++p) {
            bf16x8 af[4], bfr[4];
            #pragma unroll
            for (int t = 0; t < 4; ++t) {
                af[t]  = *(const bf16x8*)(As + p * 4096 + (wm + t * 16 + fm) * 32 + fko);
                bfr[t] = *(const bf16x8*)(Bs + p * 4096 + (wn + t * 16 + fm) * 32 + fko);
            }
            #pragma unroll
            for (int mt = 0; mt < 4; ++mt)
                #pragma unroll
                for (int nt = 0; nt < 4; ++nt)
                    acc[mt][nt] = __builtin_amdgcn_mfma_f32_16x16x32_bf16(
                        af[mt], bfr[nt], acc[mt][nt], 0, 0, 0);
        }
        __syncthreads();
    }

    // epilogue: C/D layout col=lane&15, row=(lane>>4)*4+reg [m89-verified]
    // assemble bf16 tile in LDS (stride 136), then coalesced bf16x8 stores.
    const int ecol = lane & 15;
    const int erow = (lane >> 4) * 4;
    #pragma unroll
    for (int nt = 0; nt < 4; ++nt) {
        const int cl = wn + nt * 16 + ecol;
        const float bv = bias[bn + cl];
        #pragma unroll
        for (int mt = 0; mt < 4; ++mt) {
            #pragma unroll
            for (int r = 0; r < 4; ++r) {
                const int rl = wm + mt * 16 + erow + r;
                float v = acc[mt][nt][r] + bv;
                if (RELU) v = fmaxf(v, 0.f);
                smem[rl * 136 + cl] = (__bf16)v;
            }
        }
    }
    __syncthreads();
    #pragma unroll
    for (int rr = 0; rr < 8; ++rr) {
        const int idx = rr * 256 + tid;
        if (HEADMAJOR) {
            const int plane = idx >> 9;          // 4 planes of 32 cols in this 128-col tile
            const int row   = (idx >> 2) & 127;
            const int ch4   = idx & 3;
            if (bm + row < M)
                *(bf16x8*)(C + ((size_t)((bn >> 5) + plane) * M_PAD + (bm + row)) * 32 + ch4 * 8) =
                    *(const bf16x8*)(smem + row * 136 + plane * 32 + ch4 * 8);
        } else {
            const int row = idx >> 4;
            const int ch  = idx & 15;
            if (bm + row < M)
                *(bf16x8*)(C + (size_t)(bm + row) * N + bn + ch * 8) =
                    *(const bf16x8*)(smem + row * 136 + ch * 8);
        }
    }
}

// front GEMM: blocks x<2 -> value (src_b @ Wt_value, head-major), x>=2 -> oa (q_b @ Wt_oa)
__global__ __launch_bounds__(256) void gemm_front(
    const __bf16* __restrict__ A0, const __bf16* __restrict__ B0,
    const float* __restrict__ bi0, __bf16* __restrict__ C0,
    const __bf16* __restrict__ A1, const __bf16* __restrict__ B1,
    const float* __restrict__ bi1, __bf16* __restrict__ C1, int M)
{
    const int bx = blockIdx.x;
    if (bx < 2)
        gemm_core<false, 256, true>(A0, B0, bi0, C0, M, 256, blockIdx.y * 128, bx * 128);
    else
        gemm_core<false, 256, false>(A1, B1, bi1, C1, M, 384, blockIdx.y * 128, (bx - 2) * 128);
}

// FFN1: relu(x_b @ W1 + b1), N=1024
__global__ __launch_bounds__(256) void gemm_ffn1(
    const __bf16* __restrict__ A, const __bf16* __restrict__ Bt,
    const float* __restrict__ bias, __bf16* __restrict__ C, int M)
{
    gemm_core<true, 256, false>(A, Bt, bias, C, M, 1024, blockIdx.y * 128, blockIdx.x * 128);
}

// ---------------- GEMM + residual + LayerNorm fused (32x256 tile, BK=32, 4 waves) ----------------
// BARRIER-FREE K-loop: wave wv stages and reads ONLY B rows [wv*64,wv*64+64) plus its
// own private A copy -> zero cross-wave deps. Each wave free-runs a double-buffered
// pipeline with counted s_waitcnt vmcnt(6) (6 gload_lds per stage per wave). No
// __syncthreads convoy; latency hidden per-wave + by 12 independent waves/CU.
template <typename OutT, int K>
__global__ __launch_bounds__(256, 3) void gemm_ln(
    const __bf16* __restrict__ A, const __bf16* __restrict__ Bt,
    const float* __restrict__ bias, const __bf16* __restrict__ res,
    const float* __restrict__ gamma, const float* __restrict__ beta,
    OutT* __restrict__ Cout, int M)
{
    // per buffer: A copies 4 waves x 1024 elems (8KB) + Bs 8192 elems (16KB) = 12288 elems
    // x2 buffers = 48KB. epilogue overlay: bf16 32x264=16.9KB / fp32 16x260=16.6KB in buf0.
    __shared__ __bf16 smem[2][12288];
    __shared__ float lnsum[32][4];
    __shared__ float lnsq[32][4];
    __shared__ float lnstat[32][2];

    const int tid  = threadIdx.x;
    const int lane = tid & 63;
    const int wv   = tid >> 6;
    const int bm   = blockIdx.x * 32;
    const int wn   = wv * 64;
    const int srow = lane >> 2;       // B-staging row-in-16 (lane>>2)
    const int skc  = (lane & 3) * 8;  // B-staging col chunk
    const int fm   = lane & 15;
    const int fko  = (lane >> 4) * 8;

    f32x4 acc[2][4] = {};

    // stage tile k0 into buffer b: wave-private A copy (2 instrs) + own 64 B-rows (4 instrs)
    auto stage = [&](int b, int k0) {
        __bf16* Asw = smem[b] + wv * 1024;
        __bf16* Bsw = smem[b] + 4096;
        lds_direct16(A + (size_t)(bm +  0 + srow) * K + k0 + skc, Asw);        // rows 0-15
        lds_direct16(A + (size_t)(bm + 16 + srow) * K + k0 + skc, Asw + 512);  // rows 16-31
        #pragma unroll
        for (int c = 0; c < 4; ++c) {
            const int r = wv * 64 + c * 16;
            lds_direct16(Bt + (size_t)(r + srow) * K + k0 + skc, Bsw + r * 32);
        }
    };
    auto compute = [&](int b) {
        const __bf16* Asw = smem[b] + wv * 1024;
        const __bf16* Bsw = smem[b] + 4096;
        bf16x8 af[2], bfr[4];
        #pragma unroll
        for (int mt = 0; mt < 2; ++mt)
            af[mt] = *(const bf16x8*)(Asw + (mt * 16 + fm) * 32 + fko);
        #pragma unroll
        for (int nt = 0; nt < 4; ++nt)
            bfr[nt] = *(const bf16x8*)(Bsw + (wn + nt * 16 + fm) * 32 + fko);
        #pragma unroll
        for (int mt = 0; mt < 2; ++mt)
            #pragma unroll
            for (int nt = 0; nt < 4; ++nt)
                acc[mt][nt] = __builtin_amdgcn_mfma_f32_16x16x32_bf16(
                    af[mt], bfr[nt], acc[mt][nt], 0, 0, 0);
    };

    stage(0, 0);
    int cur = 0;
    for (int k0 = 32; k0 < K; k0 += 32) {
        stage(cur ^ 1, k0);                       // 1-ahead prefetch (6 more in flight)
        asm volatile("s_waitcnt vmcnt(6)" ::: "memory");   // wait ONLY current tile's 6
        __builtin_amdgcn_sched_barrier(0);
        compute(cur);
        cur ^= 1;
    }
    asm volatile("s_waitcnt vmcnt(0)" ::: "memory");
    __builtin_amdgcn_sched_barrier(0);
    compute(cur);

    const int ecol = lane & 15;
    const int erow = (lane >> 4) * 4;

    // bias + residual
    float g4[4], b4[4];
    #pragma unroll
    for (int nt = 0; nt < 4; ++nt) {
        const int col = wn + nt * 16 + ecol;
        g4[nt] = gamma[col];
        b4[nt] = beta[col];
        const float bv = bias[col];
        #pragma unroll
        for (int mt = 0; mt < 2; ++mt) {
            #pragma unroll
            for (int r = 0; r < 4; ++r) {
                const int row = bm + mt * 16 + erow + r;
                acc[mt][nt][r] += bv + (float)res[(size_t)row * 256 + col];
            }
        }
    }

    // per-row sums (wave's 64-col slice), 16-lane shuffle reduce
    #pragma unroll
    for (int mt = 0; mt < 2; ++mt) {
        #pragma unroll
        for (int r = 0; r < 4; ++r) {
            float s  = acc[mt][0][r] + acc[mt][1][r] + acc[mt][2][r] + acc[mt][3][r];
            float s2 = acc[mt][0][r] * acc[mt][0][r] + acc[mt][1][r] * acc[mt][1][r]
                     + acc[mt][2][r] * acc[mt][2][r] + acc[mt][3][r] * acc[mt][3][r];
            #pragma unroll
            for (int o = 1; o < 16; o <<= 1) {
                s  += __shfl_xor(s, o);
                s2 += __shfl_xor(s2, o);
            }
            if (ecol == 0) {
                const int rl = mt * 16 + erow + r;
                lnsum[rl][wv] = s;
                lnsq[rl][wv]  = s2;
            }
        }
    }
    __syncthreads();
    if (tid < 32) {
        const float s  = lnsum[tid][0] + lnsum[tid][1] + lnsum[tid][2] + lnsum[tid][3];
        const float s2 = lnsq[tid][0] + lnsq[tid][1] + lnsq[tid][2] + lnsq[tid][3];
        const float mu = s * (1.f / 256.f);
        const float var = s2 * (1.f / 256.f) - mu * mu;
        lnstat[tid][0] = mu;
        lnstat[tid][1] = rsqrtf(var + 1e-5f);
    }
    __syncthreads();

    // normalize into LDS tile, then coalesced stores
    if constexpr (sizeof(OutT) == 2) {
        __bf16* ct = smem[0];   // [32][264]
        #pragma unroll
        for (int mt = 0; mt < 2; ++mt) {
            #pragma unroll
            for (int r = 0; r < 4; ++r) {
                const int rl = mt * 16 + erow + r;
                const float mu = lnstat[rl][0];
                const float rs = lnstat[rl][1];
                #pragma unroll
                for (int nt = 0; nt < 4; ++nt) {
                    const int col = wn + nt * 16 + ecol;
                    ct[rl * 264 + col] = (__bf16)((acc[mt][nt][r] - mu) * rs * g4[nt] + b4[nt]);
                }
            }
        }
        __syncthreads();
        #pragma unroll
        for (int rr = 0; rr < 4; ++rr) {
            const int idx = rr * 256 + tid;
            const int row = idx >> 5;
            const int ch  = idx & 31;
            if (bm + row < M)
                *(bf16x8*)((__bf16*)Cout + (size_t)(bm + row) * 256 + ch * 8) =
                    *(const bf16x8*)(ct + row * 264 + ch * 8);
        }
    } else {
        float* ct = (float*)smem[0];   // [16][260] per half
        #pragma unroll
        for (int hf = 0; hf < 2; ++hf) {
            const int mt = hf;
            #pragma unroll
            for (int r = 0; r < 4; ++r) {
                const int rl   = mt * 16 + erow + r;
                const int rloc = erow + r;
                const float mu = lnstat[rl][0];
                const float rs = lnstat[rl][1];
                #pragma unroll
                for (int nt = 0; nt < 4; ++nt) {
                    const int col = wn + nt * 16 + ecol;
                    ct[rloc * 260 + col] = (acc[mt][nt][r] - mu) * rs * g4[nt] + b4[nt];
                }
            }
            __syncthreads();
            #pragma unroll
            for (int rr = 0; rr < 4; ++rr) {
                const int idx = rr * 256 + tid;
                const int row = idx >> 6;
                const int ch  = idx & 63;
                const int grow = bm + hf * 16 + row;
                if (grow < M) {
                    float4 v = *(const float4*)(ct + row * 260 + ch * 4);
                    *(float4*)((float*)Cout + (size_t)grow * 256 + ch * 4) = v;
                }
            }
            __syncthreads();
        }
    }
}

// ---------------- deformable sampling ----------------
// value is HEAD-MAJOR: [8][Mpad][32] bf16. Blocks are 16 tokens x 2 HEADS
// (gridDim.y = 4 head-pairs, y is the slow dispatch dim) so the instantaneous
// gather working set is 2 planes = 3.4MB -> L2-resident per XCD (refp is
// uniform-random so token-locality doesn't exist; head-locality does).
// 256 thr = 16 tok x 2 heads x 8 lanes; per (q,dy) each lane loads dwordx4 of a
// 128B window covering both x-corners (c8 0-3: xs row, 4-7: xs+1); shfl_xor(4) folds.
__global__ __launch_bounds__(256) void msda_sample(
    const __bf16* __restrict__ value, // [8][Mpad][32] bf16, head-major planes
    const __bf16* __restrict__ oa,    // [Mpad, 384] bf16: [off(256) | attn(128)]
    const float* __restrict__ refp,   // [M, 4, 2]
    __bf16* __restrict__ out)         // [Mpad, 256] bf16
{
    __shared__ uint32_t sc[32 * 132]; // per (t,hl): 16q x 2dy x {boff,w0,w1,pad} ; 16.9 KB
    __shared__ float sw[32][16];      // softmax weights ; 2 KB

    const int tid   = threadIdx.x;
    const int blk   = blockIdx.x;        // 16-token block
    const int hbase = blockIdx.y * 2;    // head pair

    // ---- phase 1: softmax, one (token, head) per thread (32 threads = 16t x 2h)
    if (tid < 32) {
        const int t = tid >> 1;
        const int h = hbase + (tid & 1);
        int row = blk * 16 + t; if (row >= M_TOK) row = M_TOK - 1;
        const __bf16* ap = oa + (size_t)row * 384 + 256 + h * 16;
        const bf16x8 v0 = *(const bf16x8*)ap;
        const bf16x8 v1 = *(const bf16x8*)(ap + 8);
        float e[16];
        #pragma unroll
        for (int i = 0; i < 8; ++i) { e[i] = (float)v0[i]; e[8 + i] = (float)v1[i]; }
        float mx = -1e30f;
        #pragma unroll
        for (int i = 0; i < 16; ++i) mx = fmaxf(mx, e[i]);
        float s = 0.f;
        #pragma unroll
        for (int i = 0; i < 16; ++i) { e[i] = __expf(e[i] - mx); s += e[i]; }
        const float inv = 1.f / s;
        #pragma unroll
        for (int i = 0; i < 16; ++i) sw[tid][i] = e[i] * inv;   // sw index = t*2 + hl
    }
    __syncthreads();

    // ---- phase 2: per (t,hl,lp): two x-pair entries (dy=0,1); 512 items, 2/thread
    #pragma unroll
    for (int it = 0; it < 2; ++it) {
        const int idx = it * 256 + tid;       // 0..511 = t*32 + hl*16 + lp
        const int t  = idx >> 5;
        const int hl = (idx >> 4) & 1;
        const int lp = idx & 15;
        const int l  = lp >> 2;
        const int h  = hbase + hl;
        int row = blk * 16 + t; if (row >= M_TOK) row = M_TOK - 1;
        const int Ww = c_lvl_w[l];
        const int Hh = c_lvl_h[l];
        const uint32_t opk = *(const uint32_t*)(oa + (size_t)row * 384 + h * 32 + lp * 2);
        const float ox = bflo(opk), oy = bfhi(opk);
        const float rx = refp[((size_t)row * 4 + l) * 2 + 0];
        const float ry = refp[((size_t)row * 4 + l) * 2 + 1];
        const float x = (rx + ox / (float)Ww) * (float)Ww - 0.5f;
        const float y = (ry + oy / (float)Hh) * (float)Hh - 0.5f;
        const float xf = floorf(x), yf = floorf(y);
        const float fx = x - xf,    fy = y - yf;
        const int x0 = (int)xf, y0 = (int)yf;
        const int n  = (row >= LEN_IN) ? 1 : 0;
        const int lvlbase = n * LEN_IN + c_lvl_s[l];
        const float a = sw[t * 2 + hl][lp];
        // x window: xs = clamp(x0, 0, W-2); loaded positions xs, xs+1
        const int xs = min(max(x0, 0), Ww - 2);
        const int d  = x0 - xs;   // -1: only right corner (at xs); 0: both; 1: only left (at xs+1)
        const float wxl = 1.f - fx, wxr = fx;
        const float pw0 = (d == 0) ? wxl : ((d == -1) ? wxr : 0.f);
        const float pw1 = (d == 0) ? wxr : ((d == 1) ? wxl : 0.f);
        uint32_t* p = sc + (t * 2 + hl) * 132 + lp * 8;
        #pragma unroll
        for (int dy = 0; dy < 2; ++dy) {
            const int yi = y0 + dy;
            const int yc = min(max(yi, 0), Hh - 1);
            const bool yv = (yi >= 0) & (yi < Hh);
            const float wy = (dy ? fy : 1.f - fy) * (yv ? a : 0.f);
            const uint32_t boff = (uint32_t)(lvlbase + yc * Ww + xs) * 64u;  // BYTE offset in plane
            u32x4 pk = { boff, __float_as_uint(pw0 * wy), __float_as_uint(pw1 * wy), 0u };
            *(u32x4*)(p + dy * 4) = pk;
        }
    }
    __syncthreads();

    // ---- phase 3: gather. t = tid>>4, hl = (tid>>3)&1, c8 = tid&7
    const int t  = tid >> 4;
    const int hl = (tid >> 3) & 1;
    const int c8 = tid & 7;
    const int h  = hbase + hl;
    const uint32_t* mb = sc + (t * 2 + hl) * 132;
    const char* __restrict__ vpb = (const char*)(value + (size_t)h * (M_PAD * 32));
    const uint32_t lsub = (uint32_t)c8 * 16u;
    const bool hi = (c8 >= 4);
    float acc[8] = {};
    #pragma unroll 8
    for (int qd = 0; qd < 32; ++qd) {
        const u32x4 md = *(const u32x4*)(mb + qd * 4);
        const float w = __uint_as_float(hi ? md.z : md.y);
        const u32x4 v = *(const u32x4*)(vpb + (size_t)(md.x + lsub));
        #pragma unroll
        for (int d2 = 0; d2 < 4; ++d2) {
            acc[2 * d2]     += w * bflo(v[d2]);
            acc[2 * d2 + 1] += w * bfhi(v[d2]);
        }
    }
    #pragma unroll
    for (int j = 0; j < 8; ++j) acc[j] += __shfl_xor(acc[j], 4);   // fold xs/xs+1 halves
    if (c8 < 4) {
        const int orow = blk * 16 + t;
        if (orow < M_TOK) {
            bf16x8 o;
            #pragma unroll
            for (int j = 0; j < 8; ++j) o[j] = (__bf16)acc[j];
            *(bf16x8*)(out + (size_t)orow * 256 + h * 32 + c8 * 8) = o;
        }
    }
}

// ---------------- launch ----------------
extern "C" void kernel_launch(void* const* d_in, const int* in_sizes, int n_in,
                              void* d_out, int out_size, void* d_ws, size_t ws_size,
                              hipStream_t stream)
{
    const float* src     = (const float*)d_in[0];
    const float* pos     = (const float*)d_in[1];
    const float* refp    = (const float*)d_in[2];
    const float* W_value = (const float*)d_in[5];
    const float* b_value = (const float*)d_in[6];
    const float* W_off   = (const float*)d_in[7];
    const float* b_off   = (const float*)d_in[8];
    const float* W_attn  = (const float*)d_in[9];
    const float* b_attn  = (const float*)d_in[10];
    const float* W_out   = (const float*)d_in[11];
    const float* b_out   = (const float*)d_in[12];
    const float* W1      = (const float*)d_in[13];
    const float* b1      = (const float*)d_in[14];
    const float* W2      = (const float*)d_in[15];
    const float* b2      = (const float*)d_in[16];
    const float* g1      = (const float*)d_in[17];
    const float* be1     = (const float*)d_in[18];
    const float* g2      = (const float*)d_in[19];
    const float* be2     = (const float*)d_in[20];
    float* outp = (float*)d_out;

    const int M = M_TOK;
    char* ws = (char*)d_ws;
    const size_t R2 = (size_t)M_PAD * 512;   // bytes of one [Mpad,256] bf16 buffer

    __bf16* src_b = (__bf16*)(ws);                    // [0, R2)
    __bf16* q_b   = (__bf16*)(ws + R2);               // [R2, 2R2)
    __bf16* val_b = (__bf16*)(ws + 2 * R2);           // [2R2, 3R2)  head-major [8][Mpad][32]
    __bf16* oa    = (__bf16*)(ws + 3 * R2);           // [3R2, 4.5R2)
    __bf16* samp  = (__bf16*)(ws + 9 * R2 / 2);       // [4.5R2, 5.5R2)
    __bf16* x_b   = (__bf16*)(ws + 11 * R2 / 2);      // [5.5R2, 6.5R2)
    __bf16* hbuf  = (__bf16*)(ws);                    // [0, 4R2) overlay (dead by FFN1)
    __bf16* wbase = (__bf16*)(ws + 13 * R2 / 2);
    __bf16* Wt_value = wbase;                          // [256][256]
    __bf16* Wt_oa    = wbase + 65536;                  // [384][256]
    __bf16* Wt_out   = wbase + 163840;                 // [256][256]
    __bf16* Wt1      = wbase + 229376;                 // [1024][256]
    __bf16* Wt2      = wbase + 491520;                 // [256][1024]
    float*  bias_oa  = (float*)(wbase + 753664);       // [384]

    const dim3 blk(256);
    const int n4 = M * 256 / 4;
    const int gm = M_PAD / 128;  // 208

    prep<<<dim3(737 + (n4 + 255) / 256), blk, 0, stream>>>(
        W_value, W_off, W_attn, W_out, W1, W2,
        Wt_value, Wt_oa, Wt_oa + 65536, Wt_out, Wt1, Wt2,
        b_off, b_attn, bias_oa,
        (const float4*)src, (const float4*)pos, (bf16x4*)src_b, (bf16x4*)q_b, n4);

    // value (2 n-tiles, head-major) + oa (3 n-tiles): 5 x 208 = 1040 blocks
    gemm_front<<<dim3(5, gm), blk, 0, stream>>>(
        src_b, Wt_value, b_value, val_b,
        q_b,   Wt_oa,    bias_oa, oa, M);

    // 16-token x head-pair blocks; y (head pair) is slow dim -> phased 3.4MB working set
    msda_sample<<<dim3((M + 15) / 16, 4), blk, 0, stream>>>(val_b, oa, refp, samp);

    // x_b = LN(src + samp @ W_out + b_out)  (bf16), 32-row blocks, barrier-free K-loop
    gemm_ln<__bf16, 256><<<dim3(M_PAD / 32), blk, 0, stream>>>(
        samp, Wt_out, b_out, src_b, g1, be1, x_b, M);

    // hbuf = relu(x_b @ W1 + b1)
    gemm_ffn1<<<dim3(8, gm), blk, 0, stream>>>(x_b, Wt1, b1, hbuf, M);

    // out = LN(x_b + hbuf @ W2 + b2)  (fp32, to d_out), 32-row blocks, barrier-free K-loop
    gemm_ln<float, 1024><<<dim3(M_PAD / 32), blk, 0, stream>>>(
        hbuf, Wt2, b2, x_b, g2, be2, outp, M);
}

// Round 9
// 290.315 us; speedup vs baseline: 1.0694x; 1.0270x over previous
//
#include <hip/hip_runtime.h>
#include <hip/hip_bf16.h>
#include <cstdint>

// ---------------- static problem config ----------------
#define D_MODEL   256
#define N_HEADS   8
#define N_LEVELS  4
#define N_POINTS  4
#define D_FFN     1024
#define D_HEAD    32
#define LEN_IN    13294          // 100*100 + 50*50 + 25*25 + 13*13
#define NBATCH    2
#define M_TOK     (NBATCH * LEN_IN)   // 26588
#define M_PAD     26624               // 208*128 = 416*64 = 832*32

__constant__ int c_lvl_h[4] = {100, 50, 25, 13};
__constant__ int c_lvl_w[4] = {100, 50, 25, 13};
__constant__ int c_lvl_s[4] = {0, 10000, 12500, 13125};

typedef __attribute__((ext_vector_type(8))) __bf16 bf16x8;
typedef __attribute__((ext_vector_type(4))) __bf16 bf16x4;
typedef __attribute__((ext_vector_type(4))) float  f32x4;
typedef __attribute__((ext_vector_type(4))) uint32_t u32x4;

__device__ __forceinline__ float bflo(uint32_t w) { return __uint_as_float(w << 16); }
__device__ __forceinline__ float bfhi(uint32_t w) { return __uint_as_float(w & 0xffff0000u); }

// async global->LDS, 16B per lane; lds base wave-uniform (lane i lands at base + i*16)
__device__ __forceinline__ void lds_direct16(const void* g, void* l) {
    __builtin_amdgcn_global_load_lds(
        (const __attribute__((address_space(1))) uint32_t*)(uintptr_t)g,
        (__attribute__((address_space(3))) uint32_t*)(uintptr_t)l,
        16, 0, 0);
}

// ---------------- prep: weight transposes + bias concat + src/q cvt, ONE dispatch ----------------
__global__ __launch_bounds__(256) void prep(
    const float* __restrict__ s0, const float* __restrict__ s1, const float* __restrict__ s2,
    const float* __restrict__ s3, const float* __restrict__ s4, const float* __restrict__ s5,
    __bf16* __restrict__ d0, __bf16* __restrict__ d1, __bf16* __restrict__ d2,
    __bf16* __restrict__ d3, __bf16* __restrict__ d4, __bf16* __restrict__ d5,
    const float* __restrict__ b_off, const float* __restrict__ b_attn,
    float* __restrict__ bias_oa,
    const float4* __restrict__ src, const float4* __restrict__ pos,
    bf16x4* __restrict__ sb, bf16x4* __restrict__ qb, int n4)
{
    const int tid = threadIdx.x;
    const int b = blockIdx.x;
    if (b >= 737) {   // cvt path
        const int i = (b - 737) * 256 + tid;
        if (i >= n4) return;
        const float4 s = src[i];
        const float4 p = pos[i];
        bf16x4 sv = { (__bf16)s.x, (__bf16)s.y, (__bf16)s.z, (__bf16)s.w };
        bf16x4 qv = { (__bf16)(s.x + p.x), (__bf16)(s.y + p.y),
                      (__bf16)(s.z + p.z), (__bf16)(s.w + p.w) };
        sb[i] = sv;
        qb[i] = qv;
        return;
    }
    if (b == 736) {   // bias concat: [b_off(256) | b_attn(128)]
        if (tid < 256) bias_oa[tid] = b_off[tid];
        if (tid < 128) bias_oa[256 + tid] = b_attn[tid];
        return;
    }
    const int tx = tid & 31;
    const int ty = tid >> 5;
    const int starts[7] = {0, 64, 128, 160, 224, 480, 736};
    const int Ks[6] = {256, 256, 256, 256, 256, 1024};
    const int Ns[6] = {256, 256, 128, 256, 1024, 256};
    const float* srcs[6] = {s0, s1, s2, s3, s4, s5};
    __bf16* dsts[6] = {d0, d1, d2, d3, d4, d5};
    int i = 0;
    while (b >= starts[i + 1]) ++i;
    const int t = b - starts[i];
    const int K = Ks[i], N = Ns[i];
    const float* W = srcs[i];
    __bf16* Wt = dsts[i];
    const int ntx = N >> 5;
    const int n0 = (t % ntx) * 32;
    const int k0 = (t / ntx) * 32;

    __shared__ float tl[32][33];
    #pragma unroll
    for (int j = 0; j < 4; ++j)
        tl[ty + j * 8][tx] = W[(size_t)(k0 + ty + j * 8) * N + n0 + tx];
    __syncthreads();
    #pragma unroll
    for (int j = 0; j < 4; ++j)
        Wt[(size_t)(n0 + ty + j * 8) * K + k0 + tx] = (__bf16)tl[tx][ty + j * 8];
}

// ---------------- bf16 MFMA GEMM core (m97 structure, 128x128 tile, NP=2) ----------------
// HEADMAJOR: C is [col/32][Mpad][32] planes; stores remapped plane-major so each
// wave writes 1KB contiguous inside one plane (rows adjacent at 64B stride).
template <bool RELU, int K, bool HEADMAJOR>
__device__ __forceinline__ void gemm_core(
    const __bf16* __restrict__ A, const __bf16* __restrict__ Bt,
    const float* __restrict__ bias, __bf16* __restrict__ C,
    int M, int N, int bm, int bn)
{
    __shared__ __bf16 smem[17408];
    __bf16* As = smem;
    __bf16* Bs = smem + 8192;

    const int tid  = threadIdx.x;
    const int lane = tid & 63;
    const int wv   = tid >> 6;
    const int wm   = (wv >> 1) * 64;
    const int wn   = (wv & 1) * 64;
    const int srow = lane >> 2;
    const int skc  = (lane & 3) * 8;
    const int fm   = lane & 15;
    const int fko  = (lane >> 4) * 8;

    f32x4 acc[4][4] = {};

    for (int k0 = 0; k0 < K; k0 += 64) {
        #pragma unroll
        for (int p = 0; p < 2; ++p) {
            #pragma unroll
            for (int c = 0; c < 2; ++c) {
                const int r = wv * 32 + c * 16;
                lds_direct16(A  + (size_t)(bm + r + srow) * K + k0 + p * 32 + skc, As + p * 4096 + r * 32);
                lds_direct16(Bt + (size_t)(bn + r + srow) * K + k0 + p * 32 + skc, Bs + p * 4096 + r * 32);
            }
        }
        __syncthreads();

        #pragma unroll
        for (int p = 0; p < 2; ++p) {
            bf16x8 af[4], bfr[4];
            #pragma unroll
            for (int t = 0; t < 4; ++t) {
                af[t]  = *(const bf16x8*)(As + p * 4096 + (wm + t * 16 + fm) * 32 + fko);
                bfr[t] = *(const bf16x8*)(Bs + p * 4096 + (wn + t * 16 + fm) * 32 + fko);
            }
            #pragma unroll
            for (int mt = 0; mt < 4; ++mt)
                #pragma unroll
                for (int nt = 0; nt < 4; ++nt)
                    acc[mt][nt] = __builtin_amdgcn_mfma_f32_16x16x32_bf16(
                        af[mt], bfr[nt], acc[mt][nt], 0, 0, 0);
        }
        __syncthreads();
    }

    const int ecol = lane & 15;
    const int erow = (lane >> 4) * 4;
    #pragma unroll
    for (int nt = 0; nt < 4; ++nt) {
        const int cl = wn + nt * 16 + ecol;
        const float bv = bias[bn + cl];
        #pragma unroll
        for (int mt = 0; mt < 4; ++mt) {
            #pragma unroll
            for (int r = 0; r < 4; ++r) {
                const int rl = wm + mt * 16 + erow + r;
                float v = acc[mt][nt][r] + bv;
                if (RELU) v = fmaxf(v, 0.f);
                smem[rl * 136 + cl] = (__bf16)v;
            }
        }
    }
    __syncthreads();
    #pragma unroll
    for (int rr = 0; rr < 8; ++rr) {
        const int idx = rr * 256 + tid;
        if (HEADMAJOR) {
            const int plane = idx >> 9;
            const int row   = (idx >> 2) & 127;
            const int ch4   = idx & 3;
            if (bm + row < M)
                *(bf16x8*)(C + ((size_t)((bn >> 5) + plane) * M_PAD + (bm + row)) * 32 + ch4 * 8) =
                    *(const bf16x8*)(smem + row * 136 + plane * 32 + ch4 * 8);
        } else {
            const int row = idx >> 4;
            const int ch  = idx & 15;
            if (bm + row < M)
                *(bf16x8*)(C + (size_t)(bm + row) * N + bn + ch * 8) =
                    *(const bf16x8*)(smem + row * 136 + ch * 8);
        }
    }
}

// front GEMM: XCD-chunked swizzle (bijective, 1040 = 8 x 130). Each XCD owns a
// contiguous 26-mtile band -> src_b/q_b A-panels (1.7MB each) stay L2-resident.
// sel<2 -> value (head-major), sel>=2 -> oa. Output per tile identical -> bitwise-safe.
__global__ __launch_bounds__(256) void gemm_front(
    const __bf16* __restrict__ A0, const __bf16* __restrict__ B0,
    const float* __restrict__ bi0, __bf16* __restrict__ C0,
    const __bf16* __restrict__ A1, const __bf16* __restrict__ B1,
    const float* __restrict__ bi1, __bf16* __restrict__ C1, int M)
{
    const int f   = blockIdx.y * 5 + blockIdx.x;   // grid (5, 208)
    const int xcd = f & 7;
    const int j   = f >> 3;          // 0..129
    const int sel = j / 26;          // 0..4
    const int mm  = j - sel * 26;    // 0..25
    const int bm  = (xcd * 26 + mm) * 128;
    if (sel < 2)
        gemm_core<false, 256, true >(A0, B0, bi0, C0, M, 256, bm, sel * 128);
    else
        gemm_core<false, 256, false>(A1, B1, bi1, C1, M, 384, bm, (sel - 2) * 128);
}

// FFN1: relu(x_b @ W1 + b1), N=1024. XCD-chunked swizzle (1664 = 8 x 208):
// XCD k owns mtiles [26k, 26k+26) x all 8 ntiles -> x_b A-panel (1.7MB) L2-resident
// instead of being fetched by all 8 XCDs (~95MB HBM saved). Bitwise-safe remap.
__global__ __launch_bounds__(256) void gemm_ffn1(
    const __bf16* __restrict__ A, const __bf16* __restrict__ Bt,
    const float* __restrict__ bias, __bf16* __restrict__ C, int M)
{
    const int f   = blockIdx.y * 8 + blockIdx.x;   // grid (8, 208)
    const int xcd = f & 7;
    const int j   = f >> 3;          // 0..207
    const int nt_ = j / 26;          // 0..7
    const int mm  = j - nt_ * 26;    // 0..25
    gemm_core<true, 256, false>(A, Bt, bias, C, M, 1024, (xcd * 26 + mm) * 128, nt_ * 128);
}

// ---------------- GEMM + residual + LayerNorm fused (32x256 tile, BK=32, 4 waves) ----------------
// 2-phase double-buffered pipeline (R5 version): stage tile t+1 BEFORE computing
// tile t; one barrier per tile. LDS 36.8KB -> 4 blocks/CU.
template <typename OutT, int K>
__global__ __launch_bounds__(256, 4) void gemm_ln(
    const __bf16* __restrict__ A, const __bf16* __restrict__ Bt,
    const float* __restrict__ bias, const __bf16* __restrict__ res,
    const float* __restrict__ gamma, const float* __restrict__ beta,
    OutT* __restrict__ Cout, int M)
{
    // staging per buffer: As 32*32 (2KB) + Bs 256*32 (16KB) = 9216 elems (18KB); x2 buffers
    // epilogue overlay: bf16 tile 32x264 = 16.9KB; fp32 half-tile 16x260 = 16.6KB (fits buf0)
    __shared__ __bf16 smem[2][9216];
    __shared__ float lnsum[32][4];
    __shared__ float lnsq[32][4];
    __shared__ float lnstat[32][2];

    const int tid  = threadIdx.x;
    const int lane = tid & 63;
    const int wv   = tid >> 6;
    const int bm   = blockIdx.x * 32;
    const int wn   = wv * 64;
    const int srow = lane >> 2;
    const int skc  = (lane & 3) * 8;
    const int fm   = lane & 15;
    const int fko  = (lane >> 4) * 8;

    f32x4 acc[2][4] = {};

    // stage tile into buffer b at K-offset k0
    auto stage = [&](int b, int k0) {
        __bf16* As = smem[b];
        __bf16* Bs = smem[b] + 1024;
        if (tid < 128)
            lds_direct16(A + (size_t)(bm + (tid >> 2)) * K + k0 + (tid & 3) * 8,
                         As + tid * 8);
        #pragma unroll
        for (int c = 0; c < 4; ++c) {
            const int r = wv * 64 + c * 16;
            lds_direct16(Bt + (size_t)(r + srow) * K + k0 + skc, Bs + r * 32);
        }
    };
    // compute one BK=32 tile from buffer b
    auto compute = [&](int b) {
        const __bf16* As = smem[b];
        const __bf16* Bs = smem[b] + 1024;
        bf16x8 af[2], bfr[4];
        #pragma unroll
        for (int mt = 0; mt < 2; ++mt)
            af[mt] = *(const bf16x8*)(As + (mt * 16 + fm) * 32 + fko);
        #pragma unroll
        for (int nt = 0; nt < 4; ++nt)
            bfr[nt] = *(const bf16x8*)(Bs + (wn + nt * 16 + fm) * 32 + fko);
        #pragma unroll
        for (int mt = 0; mt < 2; ++mt)
            #pragma unroll
            for (int nt = 0; nt < 4; ++nt)
                acc[mt][nt] = __builtin_amdgcn_mfma_f32_16x16x32_bf16(
                    af[mt], bfr[nt], acc[mt][nt], 0, 0, 0);
    };

    stage(0, 0);
    __syncthreads();            // drains vmcnt(0): buf0 ready
    int cur = 0;
    for (int k0 = 32; k0 < K; k0 += 32) {
        stage(cur ^ 1, k0);     // issue next tile's loads FIRST (latency hides under compute)
        compute(cur);
        __syncthreads();        // vmcnt(0)+lgkm drain: next buffer ready, cur reads done
        cur ^= 1;
    }
    compute(cur);               // last tile (no further staging)

    const int ecol = lane & 15;
    const int erow = (lane >> 4) * 4;

    // bias + residual
    float g4[4], b4[4];
    #pragma unroll
    for (int nt = 0; nt < 4; ++nt) {
        const int col = wn + nt * 16 + ecol;
        g4[nt] = gamma[col];
        b4[nt] = beta[col];
        const float bv = bias[col];
        #pragma unroll
        for (int mt = 0; mt < 2; ++mt) {
            #pragma unroll
            for (int r = 0; r < 4; ++r) {
                const int row = bm + mt * 16 + erow + r;
                acc[mt][nt][r] += bv + (float)res[(size_t)row * 256 + col];
            }
        }
    }

    // per-row sums (wave's 64-col slice), 16-lane shuffle reduce
    #pragma unroll
    for (int mt = 0; mt < 2; ++mt) {
        #pragma unroll
        for (int r = 0; r < 4; ++r) {
            float s  = acc[mt][0][r] + acc[mt][1][r] + acc[mt][2][r] + acc[mt][3][r];
            float s2 = acc[mt][0][r] * acc[mt][0][r] + acc[mt][1][r] * acc[mt][1][r]
                     + acc[mt][2][r] * acc[mt][2][r] + acc[mt][3][r] * acc[mt][3][r];
            #pragma unroll
            for (int o = 1; o < 16; o <<= 1) {
                s  += __shfl_xor(s, o);
                s2 += __shfl_xor(s2, o);
            }
            if (ecol == 0) {
                const int rl = mt * 16 + erow + r;
                lnsum[rl][wv] = s;
                lnsq[rl][wv]  = s2;
            }
        }
    }
    __syncthreads();
    if (tid < 32) {
        const float s  = lnsum[tid][0] + lnsum[tid][1] + lnsum[tid][2] + lnsum[tid][3];
        const float s2 = lnsq[tid][0] + lnsq[tid][1] + lnsq[tid][2] + lnsq[tid][3];
        const float mu = s * (1.f / 256.f);
        const float var = s2 * (1.f / 256.f) - mu * mu;
        lnstat[tid][0] = mu;
        lnstat[tid][1] = rsqrtf(var + 1e-5f);
    }
    __syncthreads();

    // normalize into LDS tile, then coalesced stores
    if constexpr (sizeof(OutT) == 2) {
        __bf16* ct = smem[0];   // [32][264]
        #pragma unroll
        for (int mt = 0; mt < 2; ++mt) {
            #pragma unroll
            for (int r = 0; r < 4; ++r) {
                const int rl = mt * 16 + erow + r;
                const float mu = lnstat[rl][0];
                const float rs = lnstat[rl][1];
                #pragma unroll
                for (int nt = 0; nt < 4; ++nt) {
                    const int col = wn + nt * 16 + ecol;
                    ct[rl * 264 + col] = (__bf16)((acc[mt][nt][r] - mu) * rs * g4[nt] + b4[nt]);
                }
            }
        }
        __syncthreads();
        #pragma unroll
        for (int rr = 0; rr < 4; ++rr) {
            const int idx = rr * 256 + tid;
            const int row = idx >> 5;
            const int ch  = idx & 31;
            if (bm + row < M)
                *(bf16x8*)((__bf16*)Cout + (size_t)(bm + row) * 256 + ch * 8) =
                    *(const bf16x8*)(ct + row * 264 + ch * 8);
        }
    } else {
        float* ct = (float*)smem[0];   // [16][260] per half
        #pragma unroll
        for (int hf = 0; hf < 2; ++hf) {
            const int mt = hf;
            #pragma unroll
            for (int r = 0; r < 4; ++r) {
                const int rl   = mt * 16 + erow + r;
                const int rloc = erow + r;
                const float mu = lnstat[rl][0];
                const float rs = lnstat[rl][1];
                #pragma unroll
                for (int nt = 0; nt < 4; ++nt) {
                    const int col = wn + nt * 16 + ecol;
                    ct[rloc * 260 + col] = (acc[mt][nt][r] - mu) * rs * g4[nt] + b4[nt];
                }
            }
            __syncthreads();
            #pragma unroll
            for (int rr = 0; rr < 4; ++rr) {
                const int idx = rr * 256 + tid;
                const int row = idx >> 6;
                const int ch  = idx & 63;
                const int grow = bm + hf * 16 + row;
                if (grow < M) {
                    float4 v = *(const float4*)(ct + row * 260 + ch * 4);
                    *(float4*)((float*)Cout + (size_t)grow * 256 + ch * 4) = v;
                }
            }
            __syncthreads();
        }
    }
}

// ---------------- deformable sampling ----------------
// value is HEAD-MAJOR: [8][Mpad][32] bf16. Blocks are 16 tokens x 2 HEADS
// (gridDim.y = 4 head-pairs, slow dim) -> instantaneous working set 2 planes
// = 3.4MB. 256 thr = 16t x 2h x 8 lanes; dwordx4 gathers cover both x-corners
// (c8 0-3: xs row, 4-7: xs+1); shfl_xor(4) folds.
__global__ __launch_bounds__(256) void msda_sample(
    const __bf16* __restrict__ value, // [8][Mpad][32] bf16, head-major planes
    const __bf16* __restrict__ oa,    // [Mpad, 384] bf16: [off(256) | attn(128)]
    const float* __restrict__ refp,   // [M, 4, 2]
    __bf16* __restrict__ out)         // [Mpad, 256] bf16
{
    __shared__ uint32_t sc[32 * 132];
    __shared__ float sw[32][16];

    const int tid   = threadIdx.x;
    const int blk   = blockIdx.x;
    const int hbase = blockIdx.y * 2;

    if (tid < 32) {
        const int t = tid >> 1;
        const int h = hbase + (tid & 1);
        int row = blk * 16 + t; if (row >= M_TOK) row = M_TOK - 1;
        const __bf16* ap = oa + (size_t)row * 384 + 256 + h * 16;
        const bf16x8 v0 = *(const bf16x8*)ap;
        const bf16x8 v1 = *(const bf16x8*)(ap + 8);
        float e[16];
        #pragma unroll
        for (int i = 0; i < 8; ++i) { e[i] = (float)v0[i]; e[8 + i] = (float)v1[i]; }
        float mx = -1e30f;
        #pragma unroll
        for (int i = 0; i < 16; ++i) mx = fmaxf(mx, e[i]);
        float s = 0.f;
        #pragma unroll
        for (int i = 0; i < 16; ++i) { e[i] = __expf(e[i] - mx); s += e[i]; }
        const float inv = 1.f / s;
        #pragma unroll
        for (int i = 0; i < 16; ++i) sw[tid][i] = e[i] * inv;
    }
    __syncthreads();

    #pragma unroll
    for (int it = 0; it < 2; ++it) {
        const int idx = it * 256 + tid;
        const int t  = idx >> 5;
        const int hl = (idx >> 4) & 1;
        const int lp = idx & 15;
        const int l  = lp >> 2;
        const int h  = hbase + hl;
        int row = blk * 16 + t; if (row >= M_TOK) row = M_TOK - 1;
        const int Ww = c_lvl_w[l];
        const int Hh = c_lvl_h[l];
        const uint32_t opk = *(const uint32_t*)(oa + (size_t)row * 384 + h * 32 + lp * 2);
        const float ox = bflo(opk), oy = bfhi(opk);
        const float rx = refp[((size_t)row * 4 + l) * 2 + 0];
        const float ry = refp[((size_t)row * 4 + l) * 2 + 1];
        const float x = (rx + ox / (float)Ww) * (float)Ww - 0.5f;
        const float y = (ry + oy / (float)Hh) * (float)Hh - 0.5f;
        const float xf = floorf(x), yf = floorf(y);
        const float fx = x - xf,    fy = y - yf;
        const int x0 = (int)xf, y0 = (int)yf;
        const int n  = (row >= LEN_IN) ? 1 : 0;
        const int lvlbase = n * LEN_IN + c_lvl_s[l];
        const float a = sw[t * 2 + hl][lp];
        const int xs = min(max(x0, 0), Ww - 2);
        const int d  = x0 - xs;
        const float wxl = 1.f - fx, wxr = fx;
        const float pw0 = (d == 0) ? wxl : ((d == -1) ? wxr : 0.f);
        const float pw1 = (d == 0) ? wxr : ((d == 1) ? wxl : 0.f);
        uint32_t* p = sc + (t * 2 + hl) * 132 + lp * 8;
        #pragma unroll
        for (int dy = 0; dy < 2; ++dy) {
            const int yi = y0 + dy;
            const int yc = min(max(yi, 0), Hh - 1);
            const bool yv = (yi >= 0) & (yi < Hh);
            const float wy = (dy ? fy : 1.f - fy) * (yv ? a : 0.f);
            const uint32_t boff = (uint32_t)(lvlbase + yc * Ww + xs) * 64u;
            u32x4 pk = { boff, __float_as_uint(pw0 * wy), __float_as_uint(pw1 * wy), 0u };
            *(u32x4*)(p + dy * 4) = pk;
        }
    }
    __syncthreads();

    const int t  = tid >> 4;
    const int hl = (tid >> 3) & 1;
    const int c8 = tid & 7;
    const int h  = hbase + hl;
    const uint32_t* mb = sc + (t * 2 + hl) * 132;
    const char* __restrict__ vpb = (const char*)(value + (size_t)h * (M_PAD * 32));
    const uint32_t lsub = (uint32_t)c8 * 16u;
    const bool hi = (c8 >= 4);
    float acc[8] = {};
    #pragma unroll 8
    for (int qd = 0; qd < 32; ++qd) {
        const u32x4 md = *(const u32x4*)(mb + qd * 4);
        const float w = __uint_as_float(hi ? md.z : md.y);
        const u32x4 v = *(const u32x4*)(vpb + (size_t)(md.x + lsub));
        #pragma unroll
        for (int d2 = 0; d2 < 4; ++d2) {
            acc[2 * d2]     += w * bflo(v[d2]);
            acc[2 * d2 + 1] += w * bfhi(v[d2]);
        }
    }
    #pragma unroll
    for (int j = 0; j < 8; ++j) acc[j] += __shfl_xor(acc[j], 4);
    if (c8 < 4) {
        const int orow = blk * 16 + t;
        if (orow < M_TOK) {
            bf16x8 o;
            #pragma unroll
            for (int j = 0; j < 8; ++j) o[j] = (__bf16)acc[j];
            *(bf16x8*)(out + (size_t)orow * 256 + h * 32 + c8 * 8) = o;
        }
    }
}

// ---------------- launch ----------------
extern "C" void kernel_launch(void* const* d_in, const int* in_sizes, int n_in,
                              void* d_out, int out_size, void* d_ws, size_t ws_size,
                              hipStream_t stream)
{
    const float* src     = (const float*)d_in[0];
    const float* pos     = (const float*)d_in[1];
    const float* refp    = (const float*)d_in[2];
    const float* W_value = (const float*)d_in[5];
    const float* b_value = (const float*)d_in[6];
    const float* W_off   = (const float*)d_in[7];
    const float* b_off   = (const float*)d_in[8];
    const float* W_attn  = (const float*)d_in[9];
    const float* b_attn  = (const float*)d_in[10];
    const float* W_out   = (const float*)d_in[11];
    const float* b_out   = (const float*)d_in[12];
    const float* W1      = (const float*)d_in[13];
    const float* b1      = (const float*)d_in[14];
    const float* W2      = (const float*)d_in[15];
    const float* b2      = (const float*)d_in[16];
    const float* g1      = (const float*)d_in[17];
    const float* be1     = (const float*)d_in[18];
    const float* g2      = (const float*)d_in[19];
    const float* be2     = (const float*)d_in[20];
    float* outp = (float*)d_out;

    const int M = M_TOK;
    char* ws = (char*)d_ws;
    const size_t R2 = (size_t)M_PAD * 512;   // bytes of one [Mpad,256] bf16 buffer

    __bf16* src_b = (__bf16*)(ws);                    // [0, R2)
    __bf16* q_b   = (__bf16*)(ws + R2);               // [R2, 2R2)
    __bf16* val_b = (__bf16*)(ws + 2 * R2);           // [2R2, 3R2)  head-major [8][Mpad][32]
    __bf16* oa    = (__bf16*)(ws + 3 * R2);           // [3R2, 4.5R2)
    __bf16* samp  = (__bf16*)(ws + 9 * R2 / 2);       // [4.5R2, 5.5R2)
    __bf16* x_b   = (__bf16*)(ws + 11 * R2 / 2);      // [5.5R2, 6.5R2)
    __bf16* hbuf  = (__bf16*)(ws);                    // [0, 4R2) overlay (dead by FFN1)
    __bf16* wbase = (__bf16*)(ws + 13 * R2 / 2);
    __bf16* Wt_value = wbase;                          // [256][256]
    __bf16* Wt_oa    = wbase + 65536;                  // [384][256]
    __bf16* Wt_out   = wbase + 163840;                 // [256][256]
    __bf16* Wt1      = wbase + 229376;                 // [1024][256]
    __bf16* Wt2      = wbase + 491520;                 // [256][1024]
    float*  bias_oa  = (float*)(wbase + 753664);       // [384]

    const dim3 blk(256);
    const int n4 = M * 256 / 4;
    const int gm = M_PAD / 128;  // 208

    prep<<<dim3(737 + (n4 + 255) / 256), blk, 0, stream>>>(
        W_value, W_off, W_attn, W_out, W1, W2,
        Wt_value, Wt_oa, Wt_oa + 65536, Wt_out, Wt1, Wt2,
        b_off, b_attn, bias_oa,
        (const float4*)src, (const float4*)pos, (bf16x4*)src_b, (bf16x4*)q_b, n4);

    // value (head-major) + oa: 5 x 208 = 1040 blocks, XCD-chunked swizzle
    gemm_front<<<dim3(5, gm), blk, 0, stream>>>(
        src_b, Wt_value, b_value, val_b,
        q_b,   Wt_oa,    bias_oa, oa, M);

    // 16-token x head-pair blocks; y (head pair) is slow dim
    msda_sample<<<dim3((M + 15) / 16, 4), blk, 0, stream>>>(val_b, oa, refp, samp);

    // x_b = LN(src + samp @ W_out + b_out)  (bf16), 2-phase pipeline
    gemm_ln<__bf16, 256><<<dim3(M_PAD / 32), blk, 0, stream>>>(
        samp, Wt_out, b_out, src_b, g1, be1, x_b, M);

    // hbuf = relu(x_b @ W1 + b1), XCD-chunked swizzle
    gemm_ffn1<<<dim3(8, gm), blk, 0, stream>>>(x_b, Wt1, b1, hbuf, M);

    // out = LN(x_b + hbuf @ W2 + b2)  (fp32, to d_out), 2-phase pipeline
    gemm_ln<float, 1024><<<dim3(M_PAD / 32), blk, 0, stream>>>(
        hbuf, Wt2, b2, x_b, g2, be2, outp, M);
}